// Round 4
// baseline (2151.869 us; speedup 1.0000x reference)
//
#include <hip/hip_runtime.h>
#include <math.h>

#define NNODES 50000
#define NEDGES 800000
#define FINCH 512
#define HIDC 64
#define NHEADS 8
#define OUTC 40
#define NSLOPE 0.2f

typedef unsigned short ushort;

static __device__ __forceinline__ float leaky(float e) { return e > 0.f ? e : NSLOPE * e; }

static __device__ __forceinline__ float bf2f(ushort u) {
    union { unsigned int i; float f; } c; c.i = ((unsigned int)u) << 16; return c.f;
}
static __device__ __forceinline__ ushort f2bf(float f) {
    union { float f; unsigned int i; } c; c.f = f;
    unsigned int r = c.i + 0x7FFF + ((c.i >> 16) & 1);  // round-nearest-even
    return (ushort)(r >> 16);
}

// ---------------- edge-index dtype detection ----------------
// If the buffer is int64 (values < 2^31), every odd 32-bit word is 0.
__global__ void k_detect(const int* __restrict__ ei, int* __restrict__ flag) {
    if (threadIdx.x == 0) {
        int f = 1;
        for (int k = 0; k < 64; k++)
            if (ei[2 * k + 1] != 0) { f = 0; break; }
        *flag = f;
    }
}

static __device__ __forceinline__ int load_idx(const int* ei, int wide, int pos) {
    int v = wide ? ei[2 * (long long)pos] : ei[pos];
    v = v < 0 ? 0 : (v >= NNODES ? NNODES - 1 : v);  // defensive clamp
    return v;
}

// ---------------- graph build ----------------
__global__ void k_init_deg(int* __restrict__ deg) {
    int i = blockIdx.x * blockDim.x + threadIdx.x;
    if (i < NNODES) deg[i] = 1;  // self-loop
}

__global__ void k_count(const int* __restrict__ ei, const int* __restrict__ flag, int* __restrict__ deg) {
    int e = blockIdx.x * blockDim.x + threadIdx.x;
    if (e < NEDGES) {
        int d = load_idx(ei, *flag, NEDGES + e);
        atomicAdd(&deg[d], 1);
    }
}

// single-wave exclusive scan: lane i serially scans chunk [i*CH, i*CH+CH)
__global__ __launch_bounds__(64) void k_scan64(const int* __restrict__ deg, int* __restrict__ offs,
                                               int* __restrict__ cur) {
    const int lane = threadIdx.x;
    const int CH = (NNODES + 63) / 64;
    const int lo = lane * CH;
    const int hi = min(lo + CH, NNODES);
    int s = 0;
    for (int i = lo; i < hi; i++) s += deg[i];
    int x = s;
#pragma unroll
    for (int st = 1; st < 64; st <<= 1) {
        int v = __shfl_up(x, st);
        if (lane >= st) x += v;
    }
    int run = x - s;  // exclusive prefix of this chunk
    for (int i = lo; i < hi; i++) {
        offs[i] = run; cur[i] = run;
        run += deg[i];
    }
    if (lane == 63) offs[NNODES] = run;
}

__global__ void k_fill(const int* __restrict__ ei, const int* __restrict__ flag,
                       int* __restrict__ cur, int* __restrict__ csr) {
    int e = blockIdx.x * blockDim.x + threadIdx.x;
    if (e < NEDGES + NNODES) {
        int s, d;
        if (e < NEDGES) {
            int w = *flag;
            s = load_idx(ei, w, e);
            d = load_idx(ei, w, NEDGES + e);
        } else {
            s = e - NEDGES; d = s;
        }
        int pos = atomicAdd(&cur[d], 1);
        csr[pos] = s;
    }
}

// ---------------- GEMM: C[Mr,Nc] = A[Mr,K] @ B[K,Nc], fp32 accum ----------------
// A: fp32 (ABF16=false) or bf16 (true). B: fp32. C: bf16 (CBF16) or fp32.
template <bool ABF16, bool CBF16>
__global__ __launch_bounds__(256) void bgemm64(const void* __restrict__ Av, const float* __restrict__ B,
                                               void* __restrict__ Cv, int Mr, int Nc, int K) {
    __shared__ float As[16][68];
    __shared__ float Bs[16][68];
    int t = threadIdx.x;
    int tx = t & 15, ty = t >> 4;
    int row0 = blockIdx.y * 64, col0 = blockIdx.x * 64;
    float acc[4][4];
#pragma unroll
    for (int i = 0; i < 4; i++)
#pragma unroll
        for (int j = 0; j < 4; j++) acc[i][j] = 0.f;
    const bool fullN = (col0 + 64 <= Nc);
    for (int k0 = 0; k0 < K; k0 += 16) {
        {
            int row = t >> 2, v = t & 3;
            int gr = row0 + row;
            float a0 = 0.f, a1 = 0.f, a2 = 0.f, a3 = 0.f;
            if (gr < Mr) {
                if (ABF16) {
                    const ushort* A = (const ushort*)Av;
                    ushort4 a = *(const ushort4*)(A + (size_t)gr * K + k0 + v * 4);
                    a0 = bf2f(a.x); a1 = bf2f(a.y); a2 = bf2f(a.z); a3 = bf2f(a.w);
                } else {
                    const float* A = (const float*)Av;
                    float4 a = *(const float4*)(A + (size_t)gr * K + k0 + v * 4);
                    a0 = a.x; a1 = a.y; a2 = a.z; a3 = a.w;
                }
            }
            As[v * 4 + 0][row] = a0;
            As[v * 4 + 1][row] = a1;
            As[v * 4 + 2][row] = a2;
            As[v * 4 + 3][row] = a3;
        }
        {
            int kr = t >> 4, c4 = t & 15;
            if (fullN) {
                float4 b = *(const float4*)(B + (size_t)(k0 + kr) * Nc + col0 + c4 * 4);
                *(float4*)&Bs[kr][c4 * 4] = b;
            } else {
#pragma unroll
                for (int j = 0; j < 4; j++) {
                    int c = col0 + c4 * 4 + j;
                    Bs[kr][c4 * 4 + j] = (c < Nc) ? B[(size_t)(k0 + kr) * Nc + c] : 0.f;
                }
            }
        }
        __syncthreads();
#pragma unroll
        for (int kk = 0; kk < 16; kk++) {
            float4 a = *(const float4*)&As[kk][ty * 4];
            float4 b = *(const float4*)&Bs[kk][tx * 4];
            float av[4] = {a.x, a.y, a.z, a.w};
            float bv[4] = {b.x, b.y, b.z, b.w};
#pragma unroll
            for (int i = 0; i < 4; i++)
#pragma unroll
                for (int j = 0; j < 4; j++) acc[i][j] = fmaf(av[i], bv[j], acc[i][j]);
        }
        __syncthreads();
    }
#pragma unroll
    for (int i = 0; i < 4; i++) {
        int gr = row0 + ty * 4 + i;
        if (gr >= Mr) continue;
        if (CBF16) {
            ushort* C = (ushort*)Cv;
            if (fullN) {
                ushort4 o = make_ushort4(f2bf(acc[i][0]), f2bf(acc[i][1]), f2bf(acc[i][2]), f2bf(acc[i][3]));
                *(ushort4*)(C + (size_t)gr * Nc + col0 + tx * 4) = o;
            } else {
                for (int j = 0; j < 4; j++) {
                    int gc = col0 + tx * 4 + j;
                    if (gc < Nc) C[(size_t)gr * Nc + gc] = f2bf(acc[i][j]);
                }
            }
        } else {
            float* C = (float*)Cv;
            for (int j = 0; j < 4; j++) {
                int gc = col0 + tx * 4 + j;
                if (gc < Nc) C[(size_t)gr * Nc + gc] = acc[i][j];
            }
        }
    }
}

// ---------------- per-node attention logits, 8 heads (h in bf16, att fp32) ----------------
__global__ __launch_bounds__(256) void k_alpha8(const ushort* __restrict__ h, const float* __restrict__ att_s,
                                                const float* __restrict__ att_d, float* __restrict__ asrc,
                                                float* __restrict__ adst) {
    int gw = (blockIdx.x * 256 + threadIdx.x) >> 6;
    int lane = threadIdx.x & 63;
    if (gw >= NNODES * NHEADS) return;
    int n = gw >> 3, hh = gw & 7;
    float v = bf2f(h[(size_t)n * FINCH + hh * HIDC + lane]);
    float s1 = v * att_s[hh * HIDC + lane];
    float s2 = v * att_d[hh * HIDC + lane];
#pragma unroll
    for (int m = 32; m > 0; m >>= 1) { s1 += __shfl_xor(s1, m); s2 += __shfl_xor(s2, m); }
    if (lane == 0) { asrc[n * 8 + hh] = s1; adst[n * 8 + hh] = s2; }
}

// h3 in fp32, single head
__global__ __launch_bounds__(256) void k_alpha1(const float* __restrict__ h, const float* __restrict__ att_s,
                                                const float* __restrict__ att_d, float* __restrict__ asrc,
                                                float* __restrict__ adst) {
    int gw = (blockIdx.x * 256 + threadIdx.x) >> 6;
    int lane = threadIdx.x & 63;
    if (gw >= NNODES) return;
    float s1 = 0.f, s2 = 0.f;
    if (lane < OUTC) {
        float v = h[(size_t)gw * OUTC + lane];
        s1 = v * att_s[lane];
        s2 = v * att_d[lane];
    }
#pragma unroll
    for (int m = 32; m > 0; m >>= 1) { s1 += __shfl_xor(s1, m); s2 += __shfl_xor(s2, m); }
    if (lane == 0) { asrc[gw] = s1; adst[gw] = s2; }
}

// ---------------- aggregation: one wave per (node, head); lane owns one channel ----------------
template <bool DO_ELU>
__global__ __launch_bounds__(512) void agg_wave(const ushort* __restrict__ h, const float* __restrict__ asrc,
                                                const float* __restrict__ adst, const int* __restrict__ offs,
                                                const int* __restrict__ csr, const float* __restrict__ bias,
                                                ushort* __restrict__ out) {
    const int n = blockIdx.x;
    const int hh = threadIdx.x >> 6;   // head 0..7
    const int lane = threadIdx.x & 63; // channel within head
    const int beg = offs[n];
    const int deg = offs[n + 1] - beg;
    const float ad = adst[n * 8 + hh];

    // pass 1: max / sum-exp over incoming edges (lane-strided)
    float m = -1e30f;
    for (int i = lane; i < deg; i += 64) {
        int s = csr[beg + i];
        m = fmaxf(m, leaky(asrc[s * 8 + hh] + ad));
    }
#pragma unroll
    for (int w = 32; w > 0; w >>= 1) m = fmaxf(m, __shfl_xor(m, w));
    float ssum = 0.f;
    for (int i = lane; i < deg; i += 64) {
        int s = csr[beg + i];
        ssum += expf(leaky(asrc[s * 8 + hh] + ad) - m);
    }
#pragma unroll
    for (int w = 32; w > 0; w >>= 1) ssum += __shfl_xor(ssum, w);

    // pass 2: weighted accumulation; weights broadcast lane->wave via shuffle
    float acc = 0.f;
    for (int base = 0; base < deg; base += 64) {
        int idx = base + lane;
        float wl = 0.f; int sl = 0;
        if (idx < deg) {
            sl = csr[beg + idx];
            wl = expf(leaky(asrc[sl * 8 + hh] + ad) - m) / ssum;
        }
        int cnt = min(64, deg - base);
        for (int j = 0; j < cnt; j++) {
            float w = __shfl(wl, j);
            int s = __shfl(sl, j);
            acc = fmaf(bf2f(h[(size_t)s * FINCH + hh * HIDC + lane]), w, acc);
        }
    }
    float v = acc + bias[hh * HIDC + lane];
    if (DO_ELU) v = v > 0.f ? v : expf(v) - 1.f;
    out[(size_t)n * FINCH + hh * HIDC + lane] = f2bf(v);
}

// ---------------- layer-3: one wave per node; aggregation + bias + log_softmax (fp32 out) ----------------
__global__ __launch_bounds__(64) void agg_out(const float* __restrict__ h3, const float* __restrict__ asrc,
                                              const float* __restrict__ adst, const int* __restrict__ offs,
                                              const int* __restrict__ csr, const float* __restrict__ bias,
                                              float* __restrict__ out) {
    const int n = blockIdx.x;
    const int lane = threadIdx.x;
    const int beg = offs[n];
    const int deg = offs[n + 1] - beg;
    const float ad = adst[n];

    float m = -1e30f;
    for (int i = lane; i < deg; i += 64) {
        int s = csr[beg + i];
        m = fmaxf(m, leaky(asrc[s] + ad));
    }
#pragma unroll
    for (int w = 32; w > 0; w >>= 1) m = fmaxf(m, __shfl_xor(m, w));
    float ssum = 0.f;
    for (int i = lane; i < deg; i += 64) {
        int s = csr[beg + i];
        ssum += expf(leaky(asrc[s] + ad) - m);
    }
#pragma unroll
    for (int w = 32; w > 0; w >>= 1) ssum += __shfl_xor(ssum, w);

    float acc = 0.f;
    for (int base = 0; base < deg; base += 64) {
        int idx = base + lane;
        float wl = 0.f; int sl = 0;
        if (idx < deg) {
            sl = csr[beg + idx];
            wl = expf(leaky(asrc[sl] + ad) - m) / ssum;
        }
        int cnt = min(64, deg - base);
        for (int j = 0; j < cnt; j++) {
            float w = __shfl(wl, j);
            int s = __shfl(sl, j);
            if (lane < OUTC) acc = fmaf(h3[(size_t)s * OUTC + lane], w, acc);
        }
    }
    float v = (lane < OUTC) ? acc + bias[lane] : -1e30f;
    float mx = v;
#pragma unroll
    for (int w = 32; w > 0; w >>= 1) mx = fmaxf(mx, __shfl_xor(mx, w));
    float ex = (lane < OUTC) ? expf(v - mx) : 0.f;
    float se = ex;
#pragma unroll
    for (int w = 32; w > 0; w >>= 1) se += __shfl_xor(se, w);
    if (lane < OUTC) out[(size_t)n * OUTC + lane] = v - mx - logf(se);
}

extern "C" void kernel_launch(void* const* d_in, const int* in_sizes, int n_in,
                              void* d_out, int out_size, void* d_ws, size_t ws_size,
                              hipStream_t stream) {
    const float* x   = (const float*)d_in[0];
    const int*   ei  = (const int*)d_in[1];
    const float* W1  = (const float*)d_in[2];
    const float* as1 = (const float*)d_in[3];
    const float* ad1 = (const float*)d_in[4];
    const float* b1  = (const float*)d_in[5];
    const float* W2  = (const float*)d_in[6];
    const float* as2 = (const float*)d_in[7];
    const float* ad2 = (const float*)d_in[8];
    const float* b2  = (const float*)d_in[9];
    const float* W3  = (const float*)d_in[10];
    const float* as3 = (const float*)d_in[11];
    const float* ad3 = (const float*)d_in[12];
    const float* b3  = (const float*)d_in[13];
    float* out = (float*)d_out;

    // workspace layout (~110 MB; rounds 2-3 proved >=118 MB is safe)
    char* p = (char*)d_ws;
    ushort* bufA = (ushort*)p; p += (size_t)NNODES * FINCH * 2;   // 51.2 MB: h1/h2 bf16; later h3 fp32 (8 MB)
    ushort* bufB = (ushort*)p; p += (size_t)NNODES * FINCH * 2;   // 51.2 MB: x2/x3 bf16
    float* asrc = (float*)p; p += (size_t)NNODES * 8 * 4;         // also asc3
    float* adst = (float*)p; p += (size_t)NNODES * 8 * 4;         // also adc3
    int* flag = (int*)p; p += 16;
    int* deg  = (int*)p; p += (size_t)NNODES * 4;
    int* offs = (int*)p; p += (size_t)(NNODES + 1) * 4;
    int* cur  = (int*)p; p += (size_t)NNODES * 4;
    int* csr  = (int*)p; p += (size_t)(NEDGES + NNODES) * 4;
    float* h3 = (float*)bufA;   // aliases bufA (dead after layer-2 agg)
    float* asc3 = asrc;
    float* adc3 = adst;

    // graph build (CSR by dst, with self-loops)
    k_detect<<<1, 64, 0, stream>>>(ei, flag);
    k_init_deg<<<(NNODES + 255) / 256, 256, 0, stream>>>(deg);
    k_count<<<(NEDGES + 255) / 256, 256, 0, stream>>>(ei, flag, deg);
    k_scan64<<<1, 64, 0, stream>>>(deg, offs, cur);
    k_fill<<<(NEDGES + NNODES + 255) / 256, 256, 0, stream>>>(ei, flag, cur, csr);

    dim3 g1(8, (NNODES + 63) / 64);
    // layer 1: A = x (fp32), C = h1 (bf16)
    bgemm64<false, true><<<g1, 256, 0, stream>>>(x, W1, bufA, NNODES, 512, 512);
    k_alpha8<<<(NNODES * 8 * 64) / 256, 256, 0, stream>>>(bufA, as1, ad1, asrc, adst);
    agg_wave<true><<<NNODES, 512, 0, stream>>>(bufA, asrc, adst, offs, csr, b1, bufB);
    // layer 2: A = x2 (bf16), C = h2 (bf16)
    bgemm64<true, true><<<g1, 256, 0, stream>>>(bufB, W2, bufA, NNODES, 512, 512);
    k_alpha8<<<(NNODES * 8 * 64) / 256, 256, 0, stream>>>(bufA, as2, ad2, asrc, adst);
    agg_wave<true><<<NNODES, 512, 0, stream>>>(bufA, asrc, adst, offs, csr, b2, bufB);
    // layer 3: A = x3 (bf16), C = h3 (fp32), + fused log_softmax
    dim3 g3(1, (NNODES + 63) / 64);
    bgemm64<true, false><<<g3, 256, 0, stream>>>(bufB, W3, h3, NNODES, 40, 512);
    k_alpha1<<<(NNODES * 64 + 255) / 256, 256, 0, stream>>>(h3, as3, ad3, asc3, adc3);
    agg_out<<<NNODES, 64, 0, stream>>>(h3, asc3, adc3, offs, csr, b3, out);
}

// Round 5
// 997.568 us; speedup vs baseline: 2.1571x; 2.1571x over previous
//
#include <hip/hip_runtime.h>
#include <math.h>

#define NNODES 50000
#define NEDGES 800000
#define FINCH 512
#define HIDC 64
#define NHEADS 8
#define OUTC 40
#define NSLOPE 0.2f

typedef unsigned short ushort;
typedef __attribute__((ext_vector_type(8))) short bf16x8;
typedef __attribute__((ext_vector_type(4))) float f32x4;

static __device__ __forceinline__ float leaky(float e) { return e > 0.f ? e : NSLOPE * e; }

static __device__ __forceinline__ float bf2f(ushort u) {
    union { unsigned int i; float f; } c; c.i = ((unsigned int)u) << 16; return c.f;
}
static __device__ __forceinline__ ushort f2bf(float f) {
    union { float f; unsigned int i; } c; c.f = f;
    unsigned int r = c.i + 0x7FFF + ((c.i >> 16) & 1);  // round-nearest-even
    return (ushort)(r >> 16);
}

// ---------------- edge-index dtype detection (int64 => odd words all zero) ----------------
__global__ void k_detect(const int* __restrict__ ei, int* __restrict__ flag) {
    if (threadIdx.x == 0) {
        int f = 1;
        for (int k = 0; k < 64; k++)
            if (ei[2 * k + 1] != 0) { f = 0; break; }
        *flag = f;
    }
}

static __device__ __forceinline__ int load_idx(const int* ei, int wide, int pos) {
    int v = wide ? ei[2 * (long long)pos] : ei[pos];
    v = v < 0 ? 0 : (v >= NNODES ? NNODES - 1 : v);
    return v;
}

// ---------------- graph build ----------------
__global__ void k_init_deg(int* __restrict__ deg) {
    int i = blockIdx.x * blockDim.x + threadIdx.x;
    if (i < NNODES) deg[i] = 1;  // self-loop
}

__global__ void k_count(const int* __restrict__ ei, const int* __restrict__ flag, int* __restrict__ deg) {
    int e = blockIdx.x * blockDim.x + threadIdx.x;
    if (e < NEDGES) {
        int d = load_idx(ei, *flag, NEDGES + e);
        atomicAdd(&deg[d], 1);
    }
}

__global__ __launch_bounds__(64) void k_scan64(const int* __restrict__ deg, int* __restrict__ offs,
                                               int* __restrict__ cur) {
    const int lane = threadIdx.x;
    const int CH = (NNODES + 63) / 64;
    const int lo = lane * CH;
    const int hi = min(lo + CH, NNODES);
    int s = 0;
    for (int i = lo; i < hi; i++) s += deg[i];
    int x = s;
#pragma unroll
    for (int st = 1; st < 64; st <<= 1) {
        int v = __shfl_up(x, st);
        if (lane >= st) x += v;
    }
    int run = x - s;
    for (int i = lo; i < hi; i++) {
        offs[i] = run; cur[i] = run;
        run += deg[i];
    }
    if (lane == 63) offs[NNODES] = run;
}

__global__ void k_fill(const int* __restrict__ ei, const int* __restrict__ flag,
                       int* __restrict__ cur, int* __restrict__ csr) {
    int e = blockIdx.x * blockDim.x + threadIdx.x;
    if (e < NEDGES + NNODES) {
        int s, d;
        if (e < NEDGES) {
            int w = *flag;
            s = load_idx(ei, w, e);
            d = load_idx(ei, w, NEDGES + e);
        } else {
            s = e - NEDGES; d = s;
        }
        int pos = atomicAdd(&cur[d], 1);
        csr[pos] = s;
    }
}

// ---------------- fp32 -> bf16 bulk convert (float4 per thread) ----------------
__global__ void k_f2bf(const float* __restrict__ in, ushort* __restrict__ out, int n4) {
    int i = blockIdx.x * blockDim.x + threadIdx.x;
    if (i < n4) {
        float4 v = ((const float4*)in)[i];
        ushort4 o = make_ushort4(f2bf(v.x), f2bf(v.y), f2bf(v.z), f2bf(v.w));
        ((ushort4*)out)[i] = o;
    }
}

// ---------------- W[512][512] fp32 -> Wt[512][512] bf16 transposed ----------------
__global__ __launch_bounds__(256) void k_transpose(const float* __restrict__ W, ushort* __restrict__ Wt) {
    __shared__ float tile[32][33];
    int bx = blockIdx.x, by = blockIdx.y;
    int tx = threadIdx.x & 31, ty = threadIdx.x >> 5;  // 32 x 8
#pragma unroll
    for (int i = 0; i < 4; i++)
        tile[ty + i * 8][tx] = W[(size_t)(by * 32 + ty + i * 8) * 512 + bx * 32 + tx];
    __syncthreads();
#pragma unroll
    for (int i = 0; i < 4; i++)
        Wt[(size_t)(bx * 32 + ty + i * 8) * 512 + by * 32 + tx] = f2bf(tile[tx][ty + i * 8]);
}

// ---------------- MFMA bf16 GEMM: C[M,512] = A[M,512] @ Bt^T; Bt is [N=512][K=512] ----------------
// tile 64x128, BK=32, 4 waves: wave (wr,wc) in 2x2, each 32 rows x 64 cols.
__global__ __launch_bounds__(256) void mfma_gemm(const ushort* __restrict__ A, const ushort* __restrict__ Bt,
                                                 ushort* __restrict__ C, int M) {
    __shared__ ushort As[64][40];    // +8 pad
    __shared__ ushort Bs[128][40];
    const int t = threadIdx.x;
    const int wid = t >> 6, lane = t & 63;
    const int wr = wid >> 1, wc = wid & 1;
    const int row0 = blockIdx.y * 64, col0 = blockIdx.x * 128;
    const int l15 = lane & 15, l4 = lane >> 4;
    f32x4 acc[2][4] = {};
    const int r = t >> 2, kc = (t & 3) * 8;
    for (int k0 = 0; k0 < 512; k0 += 32) {
        {
            int gr = row0 + r;
            bf16x8 v = {};
            if (gr < M) v = *(const bf16x8*)(A + (size_t)gr * 512 + k0 + kc);
            *(bf16x8*)&As[r][kc] = v;
            *(bf16x8*)&Bs[r][kc]      = *(const bf16x8*)(Bt + (size_t)(col0 + r) * 512 + k0 + kc);
            *(bf16x8*)&Bs[r + 64][kc] = *(const bf16x8*)(Bt + (size_t)(col0 + r + 64) * 512 + k0 + kc);
        }
        __syncthreads();
        bf16x8 af[2], bfr[4];
#pragma unroll
        for (int mr = 0; mr < 2; mr++)
            af[mr] = *(const bf16x8*)&As[wr * 32 + mr * 16 + l15][l4 * 8];
#pragma unroll
        for (int nr = 0; nr < 4; nr++)
            bfr[nr] = *(const bf16x8*)&Bs[wc * 64 + nr * 16 + l15][l4 * 8];
#pragma unroll
        for (int mr = 0; mr < 2; mr++)
#pragma unroll
            for (int nr = 0; nr < 4; nr++)
                acc[mr][nr] = __builtin_amdgcn_mfma_f32_16x16x32_bf16(af[mr], bfr[nr], acc[mr][nr], 0, 0, 0);
        __syncthreads();
    }
    // epilogue: C/D layout col = lane&15, row = (lane>>4)*4 + q
#pragma unroll
    for (int mr = 0; mr < 2; mr++) {
#pragma unroll
        for (int q = 0; q < 4; q++) {
            int gr = row0 + wr * 32 + mr * 16 + l4 * 4 + q;
            if (gr >= M) continue;
#pragma unroll
            for (int nr = 0; nr < 4; nr++) {
                int gc = col0 + wc * 64 + nr * 16 + l15;
                C[(size_t)gr * 512 + gc] = f2bf(acc[mr][nr][q]);
            }
        }
    }
}

// ---------------- fp32 GEMM (layer 3 only): A bf16, B fp32, C fp32 ----------------
__global__ __launch_bounds__(256) void bgemm64(const ushort* __restrict__ A, const float* __restrict__ B,
                                               float* __restrict__ C, int Mr, int Nc, int K) {
    __shared__ float As[16][68];
    __shared__ float Bs[16][68];
    int t = threadIdx.x;
    int tx = t & 15, ty = t >> 4;
    int row0 = blockIdx.y * 64, col0 = blockIdx.x * 64;
    float acc[4][4];
#pragma unroll
    for (int i = 0; i < 4; i++)
#pragma unroll
        for (int j = 0; j < 4; j++) acc[i][j] = 0.f;
    for (int k0 = 0; k0 < K; k0 += 16) {
        {
            int row = t >> 2, v = t & 3;
            int gr = row0 + row;
            float a0 = 0.f, a1 = 0.f, a2 = 0.f, a3 = 0.f;
            if (gr < Mr) {
                ushort4 a = *(const ushort4*)(A + (size_t)gr * K + k0 + v * 4);
                a0 = bf2f(a.x); a1 = bf2f(a.y); a2 = bf2f(a.z); a3 = bf2f(a.w);
            }
            As[v * 4 + 0][row] = a0;
            As[v * 4 + 1][row] = a1;
            As[v * 4 + 2][row] = a2;
            As[v * 4 + 3][row] = a3;
        }
        {
            int kr = t >> 4, c4 = t & 15;
#pragma unroll
            for (int j = 0; j < 4; j++) {
                int c = col0 + c4 * 4 + j;
                Bs[kr][c4 * 4 + j] = (c < Nc) ? B[(size_t)(k0 + kr) * Nc + c] : 0.f;
            }
        }
        __syncthreads();
#pragma unroll
        for (int kk = 0; kk < 16; kk++) {
            float4 a = *(const float4*)&As[kk][ty * 4];
            float4 b = *(const float4*)&Bs[kk][tx * 4];
            float av[4] = {a.x, a.y, a.z, a.w};
            float bv[4] = {b.x, b.y, b.z, b.w};
#pragma unroll
            for (int i = 0; i < 4; i++)
#pragma unroll
                for (int j = 0; j < 4; j++) acc[i][j] = fmaf(av[i], bv[j], acc[i][j]);
        }
        __syncthreads();
    }
#pragma unroll
    for (int i = 0; i < 4; i++) {
        int gr = row0 + ty * 4 + i;
        if (gr >= Mr) continue;
        for (int j = 0; j < 4; j++) {
            int gc = col0 + tx * 4 + j;
            if (gc < Nc) C[(size_t)gr * Nc + gc] = acc[i][j];
        }
    }
}

// ---------------- per-node attention logits, 8 heads (h bf16) ----------------
__global__ __launch_bounds__(256) void k_alpha8(const ushort* __restrict__ h, const float* __restrict__ att_s,
                                                const float* __restrict__ att_d, float* __restrict__ asrc,
                                                float* __restrict__ adst) {
    int gw = (blockIdx.x * 256 + threadIdx.x) >> 6;
    int lane = threadIdx.x & 63;
    if (gw >= NNODES * NHEADS) return;
    int n = gw >> 3, hh = gw & 7;
    float v = bf2f(h[(size_t)n * FINCH + hh * HIDC + lane]);
    float s1 = v * att_s[hh * HIDC + lane];
    float s2 = v * att_d[hh * HIDC + lane];
#pragma unroll
    for (int m = 32; m > 0; m >>= 1) { s1 += __shfl_xor(s1, m); s2 += __shfl_xor(s2, m); }
    if (lane == 0) { asrc[n * 8 + hh] = s1; adst[n * 8 + hh] = s2; }
}

__global__ __launch_bounds__(256) void k_alpha1(const float* __restrict__ h, const float* __restrict__ att_s,
                                                const float* __restrict__ att_d, float* __restrict__ asrc,
                                                float* __restrict__ adst) {
    int gw = (blockIdx.x * 256 + threadIdx.x) >> 6;
    int lane = threadIdx.x & 63;
    if (gw >= NNODES) return;
    float s1 = 0.f, s2 = 0.f;
    if (lane < OUTC) {
        float v = h[(size_t)gw * OUTC + lane];
        s1 = v * att_s[lane];
        s2 = v * att_d[lane];
    }
#pragma unroll
    for (int m = 32; m > 0; m >>= 1) { s1 += __shfl_xor(s1, m); s2 += __shfl_xor(s2, m); }
    if (lane == 0) { asrc[gw] = s1; adst[gw] = s2; }
}

// ---------------- aggregation v2: one wave per node ----------------
// stats phase: lane = (edge_slot<<3)|head, coalesced asrc gathers, 3-shfl reduce.
// weighted phase: lane owns 8 contiguous channels (bf16x8 row loads), alpha in-lane.
template <bool DO_ELU>
__global__ __launch_bounds__(256) void agg_v2(const ushort* __restrict__ h, const float* __restrict__ asrc,
                                              const float* __restrict__ adst, const int* __restrict__ offs,
                                              const int* __restrict__ csr, const float* __restrict__ bias,
                                              ushort* __restrict__ out) {
    const int wid = threadIdx.x >> 6, lane = threadIdx.x & 63;
    const int n = blockIdx.x * 4 + wid;
    if (n >= NNODES) return;
    const int beg = offs[n], deg = offs[n + 1] - beg;
    const int h8 = lane & 7;   // head (stats layout)
    const int es = lane >> 3;  // edge slot
    const float ad_s = adst[n * 8 + h8];

    float m = -1e30f;
    for (int i = es; i < deg; i += 8) {
        int s = csr[beg + i];
        m = fmaxf(m, leaky(asrc[s * 8 + h8] + ad_s));
    }
    m = fmaxf(m, __shfl_xor(m, 8));
    m = fmaxf(m, __shfl_xor(m, 16));
    m = fmaxf(m, __shfl_xor(m, 32));

    float ss = 0.f;
    for (int i = es; i < deg; i += 8) {
        int s = csr[beg + i];
        ss += expf(leaky(asrc[s * 8 + h8] + ad_s) - m);
    }
    ss += __shfl_xor(ss, 8);
    ss += __shfl_xor(ss, 16);
    ss += __shfl_xor(ss, 32);

    // remap: lane owns channels lane*8..lane*8+7, head hc = lane>>3 (lane hc holds head hc's stats)
    const int hc = lane >> 3;
    const float mc  = __shfl(m, hc);
    const float rsc = 1.f / __shfl(ss, hc);
    const float adc = __shfl(ad_s, hc);

    float acc[8] = {0.f, 0.f, 0.f, 0.f, 0.f, 0.f, 0.f, 0.f};
    for (int j = 0; j < deg; j++) {
        int s = csr[beg + j];
        float w = expf(leaky(asrc[s * 8 + hc] + adc) - mc) * rsc;
        bf16x8 hv = *(const bf16x8*)(h + (size_t)s * FINCH + lane * 8);
#pragma unroll
        for (int c = 0; c < 8; c++) acc[c] = fmaf(bf2f((ushort)hv[c]), w, acc[c]);
    }
    ushort o[8];
#pragma unroll
    for (int c = 0; c < 8; c++) {
        float v = acc[c] + bias[lane * 8 + c];
        if (DO_ELU) v = v > 0.f ? v : expf(v) - 1.f;
        o[c] = f2bf(v);
    }
    *(bf16x8*)(out + (size_t)n * FINCH + lane * 8) = *(bf16x8*)o;
}

// ---------------- layer-3: one wave per node; agg + bias + log_softmax (fp32 out) ----------------
__global__ __launch_bounds__(64) void agg_out(const float* __restrict__ h3, const float* __restrict__ asrc,
                                              const float* __restrict__ adst, const int* __restrict__ offs,
                                              const int* __restrict__ csr, const float* __restrict__ bias,
                                              float* __restrict__ out) {
    const int n = blockIdx.x, lane = threadIdx.x;
    const int beg = offs[n], deg = offs[n + 1] - beg;
    const float ad = adst[n];

    float m = -1e30f;
    for (int i = lane; i < deg; i += 64) m = fmaxf(m, leaky(asrc[csr[beg + i]] + ad));
#pragma unroll
    for (int w = 32; w > 0; w >>= 1) m = fmaxf(m, __shfl_xor(m, w));
    float ss = 0.f;
    for (int i = lane; i < deg; i += 64) ss += expf(leaky(asrc[csr[beg + i]] + ad) - m);
#pragma unroll
    for (int w = 32; w > 0; w >>= 1) ss += __shfl_xor(ss, w);
    float rs = 1.f / ss;

    float acc = 0.f;
    for (int j = 0; j < deg; j++) {
        int s = csr[beg + j];
        float w = expf(leaky(asrc[s] + ad) - m) * rs;   // uniform across lanes
        if (lane < OUTC) acc = fmaf(h3[(size_t)s * OUTC + lane], w, acc);
    }
    float v = (lane < OUTC) ? acc + bias[lane] : -1e30f;
    float mx = v;
#pragma unroll
    for (int w = 32; w > 0; w >>= 1) mx = fmaxf(mx, __shfl_xor(mx, w));
    float ex = (lane < OUTC) ? expf(v - mx) : 0.f;
    float se = ex;
#pragma unroll
    for (int w = 32; w > 0; w >>= 1) se += __shfl_xor(se, w);
    if (lane < OUTC) out[(size_t)n * OUTC + lane] = v - mx - logf(se);
}

extern "C" void kernel_launch(void* const* d_in, const int* in_sizes, int n_in,
                              void* d_out, int out_size, void* d_ws, size_t ws_size,
                              hipStream_t stream) {
    const float* x   = (const float*)d_in[0];
    const int*   ei  = (const int*)d_in[1];
    const float* W1  = (const float*)d_in[2];
    const float* as1 = (const float*)d_in[3];
    const float* ad1 = (const float*)d_in[4];
    const float* b1  = (const float*)d_in[5];
    const float* W2  = (const float*)d_in[6];
    const float* as2 = (const float*)d_in[7];
    const float* ad2 = (const float*)d_in[8];
    const float* b2  = (const float*)d_in[9];
    const float* W3  = (const float*)d_in[10];
    const float* as3 = (const float*)d_in[11];
    const float* ad3 = (const float*)d_in[12];
    const float* b3  = (const float*)d_in[13];
    float* out = (float*)d_out;

    // workspace (~111 MB; <= proven-safe 118 MB)
    char* p = (char*)d_ws;
    ushort* bufA = (ushort*)p; p += (size_t)NNODES * FINCH * 2;   // h1/h2 bf16; h3 fp32 later
    ushort* bufB = (ushort*)p; p += (size_t)NNODES * FINCH * 2;   // x_bf16, then x2/x3 bf16
    float* asrc = (float*)p; p += (size_t)NNODES * 8 * 4;
    float* adst = (float*)p; p += (size_t)NNODES * 8 * 4;
    int* flag = (int*)p; p += 16;
    int* deg  = (int*)p; p += (size_t)NNODES * 4;
    int* offs = (int*)p; p += (size_t)(NNODES + 1) * 4;
    int* cur  = (int*)p; p += (size_t)NNODES * 4;
    int* csr  = (int*)p; p += (size_t)(NEDGES + NNODES) * 4;
    ushort* Wt1 = (ushort*)p; p += (size_t)512 * 512 * 2;
    ushort* Wt2 = (ushort*)p; p += (size_t)512 * 512 * 2;
    float* h3 = (float*)bufA;
    float* asc3 = asrc;
    float* adc3 = adst;

    // graph build (CSR by dst, with self-loops)
    k_detect<<<1, 64, 0, stream>>>(ei, flag);
    k_init_deg<<<(NNODES + 255) / 256, 256, 0, stream>>>(deg);
    k_count<<<(NEDGES + 255) / 256, 256, 0, stream>>>(ei, flag, deg);
    k_scan64<<<1, 64, 0, stream>>>(deg, offs, cur);
    k_fill<<<(NEDGES + NNODES + 255) / 256, 256, 0, stream>>>(ei, flag, cur, csr);

    // precision prep: x -> bf16 (bufB), W1/W2 -> bf16 transposed [N][K]
    {
        int n4 = NNODES * FINCH / 4;
        k_f2bf<<<(n4 + 255) / 256, 256, 0, stream>>>(x, bufB, n4);
        dim3 gt(16, 16);
        k_transpose<<<gt, 256, 0, stream>>>(W1, Wt1);
        k_transpose<<<gt, 256, 0, stream>>>(W2, Wt2);
    }

    dim3 gg(4, (NNODES + 63) / 64);   // 128-col x 64-row tiles
    int gagg = (NNODES + 3) / 4;
    // layer 1
    mfma_gemm<<<gg, 256, 0, stream>>>(bufB, Wt1, bufA, NNODES);
    k_alpha8<<<(NNODES * 8 * 64) / 256, 256, 0, stream>>>(bufA, as1, ad1, asrc, adst);
    agg_v2<true><<<gagg, 256, 0, stream>>>(bufA, asrc, adst, offs, csr, b1, bufB);
    // layer 2
    mfma_gemm<<<gg, 256, 0, stream>>>(bufB, Wt2, bufA, NNODES);
    k_alpha8<<<(NNODES * 8 * 64) / 256, 256, 0, stream>>>(bufA, as2, ad2, asrc, adst);
    agg_v2<true><<<gagg, 256, 0, stream>>>(bufA, asrc, adst, offs, csr, b2, bufB);
    // layer 3 (+ fused log_softmax)
    dim3 g3(1, (NNODES + 63) / 64);
    bgemm64<<<g3, 256, 0, stream>>>(bufB, W3, h3, NNODES, OUTC, 512);
    k_alpha1<<<(NNODES * 64 + 255) / 256, 256, 0, stream>>>(h3, as3, ad3, asc3, adc3);
    agg_out<<<NNODES, 64, 0, stream>>>(h3, asc3, adc3, offs, csr, b3, out);
}

// Round 6
// 798.556 us; speedup vs baseline: 2.6947x; 1.2492x over previous
//
#include <hip/hip_runtime.h>
#include <math.h>

#define NNODES 50000
#define NEDGES 800000
#define FINCH 512
#define HIDC 64
#define NHEADS 8
#define OUTC 40
#define NSLOPE 0.2f
#define NSB ((NNODES + 255) / 256)

typedef unsigned short ushort;
typedef __attribute__((ext_vector_type(8))) short bf16x8;
typedef __attribute__((ext_vector_type(4))) float f32x4;

static __device__ __forceinline__ float leaky(float e) { return e > 0.f ? e : NSLOPE * e; }

static __device__ __forceinline__ float bf2f(ushort u) {
    union { unsigned int i; float f; } c; c.i = ((unsigned int)u) << 16; return c.f;
}
static __device__ __forceinline__ ushort f2bf(float f) {
    union { float f; unsigned int i; } c; c.f = f;
    unsigned int r = c.i + 0x7FFF + ((c.i >> 16) & 1);  // round-nearest-even
    return (ushort)(r >> 16);
}

// ---------------- edge-index dtype detection (int64 => odd words all zero) ----------------
__global__ __launch_bounds__(64) void k_detect(const int* __restrict__ ei, int* __restrict__ flag) {
    int lane = threadIdx.x;
    int v = ei[2 * lane + 1];
    unsigned long long b = __ballot(v != 0);
    if (lane == 0) *flag = (b == 0ULL) ? 1 : 0;
}

static __device__ __forceinline__ int load_idx(const int* ei, int wide, int pos) {
    int v = wide ? ei[2 * (long long)pos] : ei[pos];
    v = v < 0 ? 0 : (v >= NNODES ? NNODES - 1 : v);
    return v;
}

// ---------------- graph build ----------------
__global__ void k_init_deg(int* __restrict__ deg) {
    int i = blockIdx.x * blockDim.x + threadIdx.x;
    if (i < NNODES) deg[i] = 1;  // self-loop
}

__global__ void k_count(const int* __restrict__ ei, const int* __restrict__ flag, int* __restrict__ deg) {
    int e = blockIdx.x * blockDim.x + threadIdx.x;
    if (e < NEDGES) {
        int d = load_idx(ei, *flag, NEDGES + e);
        atomicAdd(&deg[d], 1);
    }
}

// ---- hierarchical exclusive scan: block sums -> scan of sums -> block-local scan ----
__global__ __launch_bounds__(256) void k_bsum(const int* __restrict__ deg, int* __restrict__ bsum) {
    int i = blockIdx.x * 256 + threadIdx.x;
    int v = (i < NNODES) ? deg[i] : 0;
#pragma unroll
    for (int m = 32; m > 0; m >>= 1) v += __shfl_xor(v, m);
    __shared__ int ws[4];
    int wid = threadIdx.x >> 6, lane = threadIdx.x & 63;
    if (lane == 0) ws[wid] = v;
    __syncthreads();
    if (threadIdx.x == 0) bsum[blockIdx.x] = ws[0] + ws[1] + ws[2] + ws[3];
}

__global__ __launch_bounds__(64) void k_bscan(const int* __restrict__ bsum, int* __restrict__ bofs,
                                              int* __restrict__ offs) {
    const int lane = threadIdx.x;
    const int CH = (NSB + 63) / 64;
    int lo = lane * CH, hi = min(lo + CH, NSB);
    int s = 0;
    for (int i = lo; i < hi; i++) s += bsum[i];
    int x = s;
#pragma unroll
    for (int st = 1; st < 64; st <<= 1) { int v = __shfl_up(x, st); if (lane >= st) x += v; }
    int run = x - s;
    for (int i = lo; i < hi; i++) { bofs[i] = run; run += bsum[i]; }
    if (lane == 63) offs[NNODES] = run;
}

__global__ __launch_bounds__(256) void k_scan_final(const int* __restrict__ deg, const int* __restrict__ bofs,
                                                    int* __restrict__ offs, int* __restrict__ cur) {
    int b = blockIdx.x;
    int i = b * 256 + threadIdx.x;
    int v = (i < NNODES) ? deg[i] : 0;
    int lane = threadIdx.x & 63, wid = threadIdx.x >> 6;
    int x = v;
#pragma unroll
    for (int st = 1; st < 64; st <<= 1) { int t = __shfl_up(x, st); if (lane >= st) x += t; }
    __shared__ int ws[4];
    if (lane == 63) ws[wid] = x;
    __syncthreads();
    int wofs = 0;
#pragma unroll
    for (int w = 0; w < 4; w++) if (w < wid) wofs += ws[w];
    int excl = bofs[b] + wofs + x - v;
    if (i < NNODES) { offs[i] = excl; cur[i] = excl; }
}

__global__ void k_fill(const int* __restrict__ ei, const int* __restrict__ flag,
                       int* __restrict__ cur, int* __restrict__ csr) {
    int e = blockIdx.x * blockDim.x + threadIdx.x;
    if (e < NEDGES + NNODES) {
        int s, d;
        if (e < NEDGES) {
            int w = *flag;
            s = load_idx(ei, w, e);
            d = load_idx(ei, w, NEDGES + e);
        } else {
            s = e - NEDGES; d = s;
        }
        int pos = atomicAdd(&cur[d], 1);
        csr[pos] = s;
    }
}

// ---------------- fp32 -> bf16 bulk convert ----------------
__global__ void k_f2bf(const float* __restrict__ in, ushort* __restrict__ out, int n4) {
    int i = blockIdx.x * blockDim.x + threadIdx.x;
    if (i < n4) {
        float4 v = ((const float4*)in)[i];
        ushort4 o = make_ushort4(f2bf(v.x), f2bf(v.y), f2bf(v.z), f2bf(v.w));
        ((ushort4*)out)[i] = o;
    }
}

// ---------------- W[512][512] fp32 -> Wt[512][512] bf16 transposed ----------------
__global__ __launch_bounds__(256) void k_transpose(const float* __restrict__ W, ushort* __restrict__ Wt) {
    __shared__ float tile[32][33];
    int bx = blockIdx.x, by = blockIdx.y;
    int tx = threadIdx.x & 31, ty = threadIdx.x >> 5;  // 32 x 8
#pragma unroll
    for (int i = 0; i < 4; i++)
        tile[ty + i * 8][tx] = W[(size_t)(by * 32 + ty + i * 8) * 512 + bx * 32 + tx];
    __syncthreads();
#pragma unroll
    for (int i = 0; i < 4; i++)
        Wt[(size_t)(bx * 32 + ty + i * 8) * 512 + by * 32 + tx] = f2bf(tile[tx][ty + i * 8]);
}

// ---------------- MFMA bf16 GEMM: C[M,512] = A[M,512] @ Bt^T; Bt is [N=512][K=512] ----------------
__global__ __launch_bounds__(256) void mfma_gemm(const ushort* __restrict__ A, const ushort* __restrict__ Bt,
                                                 ushort* __restrict__ C, int M) {
    __shared__ ushort As[64][40];    // +8 pad
    __shared__ ushort Bs[128][40];
    const int t = threadIdx.x;
    const int wid = t >> 6, lane = t & 63;
    const int wr = wid >> 1, wc = wid & 1;
    const int row0 = blockIdx.y * 64, col0 = blockIdx.x * 128;
    const int l15 = lane & 15, l4 = lane >> 4;
    f32x4 acc[2][4] = {};
    const int r = t >> 2, kc = (t & 3) * 8;
    for (int k0 = 0; k0 < 512; k0 += 32) {
        {
            int gr = row0 + r;
            bf16x8 v = {};
            if (gr < M) v = *(const bf16x8*)(A + (size_t)gr * 512 + k0 + kc);
            *(bf16x8*)&As[r][kc] = v;
            *(bf16x8*)&Bs[r][kc]      = *(const bf16x8*)(Bt + (size_t)(col0 + r) * 512 + k0 + kc);
            *(bf16x8*)&Bs[r + 64][kc] = *(const bf16x8*)(Bt + (size_t)(col0 + r + 64) * 512 + k0 + kc);
        }
        __syncthreads();
        bf16x8 af[2], bfr[4];
#pragma unroll
        for (int mr = 0; mr < 2; mr++)
            af[mr] = *(const bf16x8*)&As[wr * 32 + mr * 16 + l15][l4 * 8];
#pragma unroll
        for (int nr = 0; nr < 4; nr++)
            bfr[nr] = *(const bf16x8*)&Bs[wc * 64 + nr * 16 + l15][l4 * 8];
#pragma unroll
        for (int mr = 0; mr < 2; mr++)
#pragma unroll
            for (int nr = 0; nr < 4; nr++)
                acc[mr][nr] = __builtin_amdgcn_mfma_f32_16x16x32_bf16(af[mr], bfr[nr], acc[mr][nr], 0, 0, 0);
        __syncthreads();
    }
#pragma unroll
    for (int mr = 0; mr < 2; mr++) {
#pragma unroll
        for (int q = 0; q < 4; q++) {
            int gr = row0 + wr * 32 + mr * 16 + l4 * 4 + q;
            if (gr >= M) continue;
#pragma unroll
            for (int nr = 0; nr < 4; nr++) {
                int gc = col0 + wc * 64 + nr * 16 + l15;
                C[(size_t)gr * 512 + gc] = f2bf(acc[mr][nr][q]);
            }
        }
    }
}

// ---------------- fp32 GEMM (layer 3 only): A bf16, B fp32, C fp32 ----------------
__global__ __launch_bounds__(256) void bgemm64(const ushort* __restrict__ A, const float* __restrict__ B,
                                               float* __restrict__ C, int Mr, int Nc, int K) {
    __shared__ float As[16][68];
    __shared__ float Bs[16][68];
    int t = threadIdx.x;
    int tx = t & 15, ty = t >> 4;
    int row0 = blockIdx.y * 64, col0 = blockIdx.x * 64;
    float acc[4][4];
#pragma unroll
    for (int i = 0; i < 4; i++)
#pragma unroll
        for (int j = 0; j < 4; j++) acc[i][j] = 0.f;
    for (int k0 = 0; k0 < K; k0 += 16) {
        {
            int row = t >> 2, v = t & 3;
            int gr = row0 + row;
            float a0 = 0.f, a1 = 0.f, a2 = 0.f, a3 = 0.f;
            if (gr < Mr) {
                ushort4 a = *(const ushort4*)(A + (size_t)gr * K + k0 + v * 4);
                a0 = bf2f(a.x); a1 = bf2f(a.y); a2 = bf2f(a.z); a3 = bf2f(a.w);
            }
            As[v * 4 + 0][row] = a0;
            As[v * 4 + 1][row] = a1;
            As[v * 4 + 2][row] = a2;
            As[v * 4 + 3][row] = a3;
        }
        {
            int kr = t >> 4, c4 = t & 15;
#pragma unroll
            for (int j = 0; j < 4; j++) {
                int c = col0 + c4 * 4 + j;
                Bs[kr][c4 * 4 + j] = (c < Nc) ? B[(size_t)(k0 + kr) * Nc + c] : 0.f;
            }
        }
        __syncthreads();
#pragma unroll
        for (int kk = 0; kk < 16; kk++) {
            float4 a = *(const float4*)&As[kk][ty * 4];
            float4 b = *(const float4*)&Bs[kk][tx * 4];
            float av[4] = {a.x, a.y, a.z, a.w};
            float bv[4] = {b.x, b.y, b.z, b.w};
#pragma unroll
            for (int i = 0; i < 4; i++)
#pragma unroll
                for (int j = 0; j < 4; j++) acc[i][j] = fmaf(av[i], bv[j], acc[i][j]);
        }
        __syncthreads();
    }
#pragma unroll
    for (int i = 0; i < 4; i++) {
        int gr = row0 + ty * 4 + i;
        if (gr >= Mr) continue;
        for (int j = 0; j < 4; j++) {
            int gc = col0 + tx * 4 + j;
            if (gc < Nc) C[(size_t)gr * Nc + gc] = acc[i][j];
        }
    }
}

// ---------------- per-node attention logits, 8 heads (h bf16) ----------------
__global__ __launch_bounds__(256) void k_alpha8(const ushort* __restrict__ h, const float* __restrict__ att_s,
                                                const float* __restrict__ att_d, float* __restrict__ asrc,
                                                float* __restrict__ adst) {
    int gw = (blockIdx.x * 256 + threadIdx.x) >> 6;
    int lane = threadIdx.x & 63;
    if (gw >= NNODES * NHEADS) return;
    int n = gw >> 3, hh = gw & 7;
    float v = bf2f(h[(size_t)n * FINCH + hh * HIDC + lane]);
    float s1 = v * att_s[hh * HIDC + lane];
    float s2 = v * att_d[hh * HIDC + lane];
#pragma unroll
    for (int m = 32; m > 0; m >>= 1) { s1 += __shfl_xor(s1, m); s2 += __shfl_xor(s2, m); }
    if (lane == 0) { asrc[n * 8 + hh] = s1; adst[n * 8 + hh] = s2; }
}

__global__ __launch_bounds__(256) void k_alpha1(const float* __restrict__ h, const float* __restrict__ att_s,
                                                const float* __restrict__ att_d, float* __restrict__ asrc,
                                                float* __restrict__ adst) {
    int gw = (blockIdx.x * 256 + threadIdx.x) >> 6;
    int lane = threadIdx.x & 63;
    if (gw >= NNODES) return;
    float s1 = 0.f, s2 = 0.f;
    if (lane < OUTC) {
        float v = h[(size_t)gw * OUTC + lane];
        s1 = v * att_s[lane];
        s2 = v * att_d[lane];
    }
#pragma unroll
    for (int m = 32; m > 0; m >>= 1) { s1 += __shfl_xor(s1, m); s2 += __shfl_xor(s2, m); }
    if (lane == 0) { asrc[gw] = s1; adst[gw] = s2; }
}

// ---------------- aggregation v2: one wave per node ----------------
template <bool DO_ELU>
__global__ __launch_bounds__(256) void agg_v2(const ushort* __restrict__ h, const float* __restrict__ asrc,
                                              const float* __restrict__ adst, const int* __restrict__ offs,
                                              const int* __restrict__ csr, const float* __restrict__ bias,
                                              ushort* __restrict__ out) {
    const int wid = threadIdx.x >> 6, lane = threadIdx.x & 63;
    const int n = blockIdx.x * 4 + wid;
    if (n >= NNODES) return;
    const int beg = offs[n], deg = offs[n + 1] - beg;
    const int h8 = lane & 7;   // head (stats layout)
    const int es = lane >> 3;  // edge slot
    const float ad_s = adst[n * 8 + h8];

    float m = -1e30f;
    for (int i = es; i < deg; i += 8) {
        int s = csr[beg + i];
        m = fmaxf(m, leaky(asrc[s * 8 + h8] + ad_s));
    }
    m = fmaxf(m, __shfl_xor(m, 8));
    m = fmaxf(m, __shfl_xor(m, 16));
    m = fmaxf(m, __shfl_xor(m, 32));

    float ss = 0.f;
    for (int i = es; i < deg; i += 8) {
        int s = csr[beg + i];
        ss += expf(leaky(asrc[s * 8 + h8] + ad_s) - m);
    }
    ss += __shfl_xor(ss, 8);
    ss += __shfl_xor(ss, 16);
    ss += __shfl_xor(ss, 32);

    const int hc = lane >> 3;
    const float mc  = __shfl(m, hc);
    const float rsc = 1.f / __shfl(ss, hc);
    const float adc = __shfl(ad_s, hc);

    float acc[8] = {0.f, 0.f, 0.f, 0.f, 0.f, 0.f, 0.f, 0.f};
    for (int j = 0; j < deg; j++) {
        int s = csr[beg + j];
        float w = expf(leaky(asrc[s * 8 + hc] + adc) - mc) * rsc;
        bf16x8 hv = *(const bf16x8*)(h + (size_t)s * FINCH + lane * 8);
#pragma unroll
        for (int c = 0; c < 8; c++) acc[c] = fmaf(bf2f((ushort)hv[c]), w, acc[c]);
    }
    ushort o[8];
#pragma unroll
    for (int c = 0; c < 8; c++) {
        float v = acc[c] + bias[lane * 8 + c];
        if (DO_ELU) v = v > 0.f ? v : expf(v) - 1.f;
        o[c] = f2bf(v);
    }
    *(bf16x8*)(out + (size_t)n * FINCH + lane * 8) = *(bf16x8*)o;
}

// ---------------- layer-3: one wave per node; agg + bias + log_softmax (fp32 out) ----------------
__global__ __launch_bounds__(64) void agg_out(const float* __restrict__ h3, const float* __restrict__ asrc,
                                              const float* __restrict__ adst, const int* __restrict__ offs,
                                              const int* __restrict__ csr, const float* __restrict__ bias,
                                              float* __restrict__ out) {
    const int n = blockIdx.x, lane = threadIdx.x;
    const int beg = offs[n], deg = offs[n + 1] - beg;
    const float ad = adst[n];

    float m = -1e30f;
    for (int i = lane; i < deg; i += 64) m = fmaxf(m, leaky(asrc[csr[beg + i]] + ad));
#pragma unroll
    for (int w = 32; w > 0; w >>= 1) m = fmaxf(m, __shfl_xor(m, w));
    float ss = 0.f;
    for (int i = lane; i < deg; i += 64) ss += expf(leaky(asrc[csr[beg + i]] + ad) - m);
#pragma unroll
    for (int w = 32; w > 0; w >>= 1) ss += __shfl_xor(ss, w);
    float rs = 1.f / ss;

    float acc = 0.f;
    for (int j = 0; j < deg; j++) {
        int s = csr[beg + j];
        float w = expf(leaky(asrc[s] + ad) - m) * rs;
        if (lane < OUTC) acc = fmaf(h3[(size_t)s * OUTC + lane], w, acc);
    }
    float v = (lane < OUTC) ? acc + bias[lane] : -1e30f;
    float mx = v;
#pragma unroll
    for (int w = 32; w > 0; w >>= 1) mx = fmaxf(mx, __shfl_xor(mx, w));
    float ex = (lane < OUTC) ? expf(v - mx) : 0.f;
    float se = ex;
#pragma unroll
    for (int w = 32; w > 0; w >>= 1) se += __shfl_xor(se, w);
    if (lane < OUTC) out[(size_t)n * OUTC + lane] = v - mx - logf(se);
}

extern "C" void kernel_launch(void* const* d_in, const int* in_sizes, int n_in,
                              void* d_out, int out_size, void* d_ws, size_t ws_size,
                              hipStream_t stream) {
    const float* x   = (const float*)d_in[0];
    const int*   ei  = (const int*)d_in[1];
    const float* W1  = (const float*)d_in[2];
    const float* as1 = (const float*)d_in[3];
    const float* ad1 = (const float*)d_in[4];
    const float* b1  = (const float*)d_in[5];
    const float* W2  = (const float*)d_in[6];
    const float* as2 = (const float*)d_in[7];
    const float* ad2 = (const float*)d_in[8];
    const float* b2  = (const float*)d_in[9];
    const float* W3  = (const float*)d_in[10];
    const float* as3 = (const float*)d_in[11];
    const float* ad3 = (const float*)d_in[12];
    const float* b3  = (const float*)d_in[13];
    float* out = (float*)d_out;

    // workspace (~111 MB; <= proven-safe 118 MB)
    char* p = (char*)d_ws;
    ushort* bufA = (ushort*)p; p += (size_t)NNODES * FINCH * 2;   // h1/h2 bf16; h3 fp32 later
    ushort* bufB = (ushort*)p; p += (size_t)NNODES * FINCH * 2;   // x_bf16, then x2/x3 bf16
    float* asrc = (float*)p; p += (size_t)NNODES * 8 * 4;
    float* adst = (float*)p; p += (size_t)NNODES * 8 * 4;
    int* flag = (int*)p; p += 16;
    int* deg  = (int*)p; p += (size_t)NNODES * 4;
    int* offs = (int*)p; p += (size_t)(NNODES + 1) * 4;
    int* cur  = (int*)p; p += (size_t)NNODES * 4;
    int* csr  = (int*)p; p += (size_t)(NEDGES + NNODES) * 4;
    ushort* Wt1 = (ushort*)p; p += (size_t)512 * 512 * 2;
    ushort* Wt2 = (ushort*)p; p += (size_t)512 * 512 * 2;
    int* bsum = (int*)p; p += (size_t)NSB * 4;
    int* bofs = (int*)p; p += (size_t)NSB * 4;
    float* h3 = (float*)bufA;
    float* asc3 = asrc;
    float* adc3 = adst;

    // graph build (CSR by dst, with self-loops)
    k_detect<<<1, 64, 0, stream>>>(ei, flag);
    k_init_deg<<<(NNODES + 255) / 256, 256, 0, stream>>>(deg);
    k_count<<<(NEDGES + 255) / 256, 256, 0, stream>>>(ei, flag, deg);
    k_bsum<<<NSB, 256, 0, stream>>>(deg, bsum);
    k_bscan<<<1, 64, 0, stream>>>(bsum, bofs, offs);
    k_scan_final<<<NSB, 256, 0, stream>>>(deg, bofs, offs, cur);
    k_fill<<<(NEDGES + NNODES + 255) / 256, 256, 0, stream>>>(ei, flag, cur, csr);

    // precision prep: x -> bf16 (bufB), W1/W2 -> bf16 transposed [N][K]
    {
        int n4 = NNODES * FINCH / 4;
        k_f2bf<<<(n4 + 255) / 256, 256, 0, stream>>>(x, bufB, n4);
        dim3 gt(16, 16);
        k_transpose<<<gt, 256, 0, stream>>>(W1, Wt1);
        k_transpose<<<gt, 256, 0, stream>>>(W2, Wt2);
    }

    dim3 gg(4, (NNODES + 63) / 64);
    int gagg = (NNODES + 3) / 4;
    // layer 1
    mfma_gemm<<<gg, 256, 0, stream>>>(bufB, Wt1, bufA, NNODES);
    k_alpha8<<<(NNODES * 8 * 64) / 256, 256, 0, stream>>>(bufA, as1, ad1, asrc, adst);
    agg_v2<true><<<gagg, 256, 0, stream>>>(bufA, asrc, adst, offs, csr, b1, bufB);
    // layer 2
    mfma_gemm<<<gg, 256, 0, stream>>>(bufB, Wt2, bufA, NNODES);
    k_alpha8<<<(NNODES * 8 * 64) / 256, 256, 0, stream>>>(bufA, as2, ad2, asrc, adst);
    agg_v2<true><<<gagg, 256, 0, stream>>>(bufA, asrc, adst, offs, csr, b2, bufB);
    // layer 3 (+ fused log_softmax)
    dim3 g3(1, (NNODES + 63) / 64);
    bgemm64<<<g3, 256, 0, stream>>>(bufB, W3, h3, NNODES, OUTC, 512);
    k_alpha1<<<(NNODES * 64 + 255) / 256, 256, 0, stream>>>(h3, as3, ad3, asc3, adc3);
    agg_out<<<NNODES, 64, 0, stream>>>(h3, asc3, adc3, offs, csr, b3, out);
}

// Round 7
// 770.046 us; speedup vs baseline: 2.7945x; 1.0370x over previous
//
#include <hip/hip_runtime.h>
#include <math.h>

#define NNODES 50000
#define NEDGES 800000
#define FINCH 512
#define HIDC 64
#define NHEADS 8
#define OUTC 40
#define NSLOPE 0.2f
#define NSB ((NNODES + 255) / 256)

typedef unsigned short ushort;
typedef unsigned int uint;
typedef __attribute__((ext_vector_type(8))) short bf16x8;
typedef __attribute__((ext_vector_type(4))) float f32x4;

static __device__ __forceinline__ float leaky(float e) { return e > 0.f ? e : NSLOPE * e; }

static __device__ __forceinline__ float bf2f(ushort u) {
    union { unsigned int i; float f; } c; c.i = ((unsigned int)u) << 16; return c.f;
}
static __device__ __forceinline__ ushort f2bf(float f) {
    union { float f; unsigned int i; } c; c.f = f;
    unsigned int r = c.i + 0x7FFF + ((c.i >> 16) & 1);  // round-nearest-even
    return (ushort)(r >> 16);
}
// order-preserving float<->uint key (for atomicMax on floats)
static __device__ __forceinline__ uint fkey(float f) {
    uint u = __float_as_uint(f);
    return (u & 0x80000000u) ? ~u : (u | 0x80000000u);
}
static __device__ __forceinline__ float fdec(uint k) {
    return __uint_as_float((k & 0x80000000u) ? (k & 0x7fffffffu) : ~k);
}

// ---------------- edge dtype detect + key init ----------------
__global__ __launch_bounds__(64) void k_detect(const int* __restrict__ ei, int* __restrict__ flag,
                                               uint* __restrict__ keys) {
    int lane = threadIdx.x;
    if (lane < 17) keys[lane] = fkey(-3.0e38f);
    int v = ei[2 * lane + 1];
    unsigned long long b = __ballot(v != 0);
    if (lane == 0) *flag = (b == 0ULL) ? 1 : 0;
}

static __device__ __forceinline__ int load_idx(const int* ei, int wide, int pos) {
    int v = wide ? ei[2 * (long long)pos] : ei[pos];
    v = v < 0 ? 0 : (v >= NNODES ? NNODES - 1 : v);
    return v;
}

// ---------------- graph build ----------------
__global__ void k_init_deg(int* __restrict__ deg) {
    int i = blockIdx.x * blockDim.x + threadIdx.x;
    if (i < NNODES) deg[i] = 1;  // self-loop
}

__global__ void k_count(const int* __restrict__ ei, const int* __restrict__ flag, int* __restrict__ deg) {
    int e = blockIdx.x * blockDim.x + threadIdx.x;
    if (e < NEDGES) {
        int d = load_idx(ei, *flag, NEDGES + e);
        atomicAdd(&deg[d], 1);
    }
}

__global__ __launch_bounds__(256) void k_bsum(const int* __restrict__ deg, int* __restrict__ bsum) {
    int i = blockIdx.x * 256 + threadIdx.x;
    int v = (i < NNODES) ? deg[i] : 0;
#pragma unroll
    for (int m = 32; m > 0; m >>= 1) v += __shfl_xor(v, m);
    __shared__ int ws[4];
    int wid = threadIdx.x >> 6, lane = threadIdx.x & 63;
    if (lane == 0) ws[wid] = v;
    __syncthreads();
    if (threadIdx.x == 0) bsum[blockIdx.x] = ws[0] + ws[1] + ws[2] + ws[3];
}

__global__ __launch_bounds__(64) void k_bscan(const int* __restrict__ bsum, int* __restrict__ bofs,
                                              int* __restrict__ offs) {
    const int lane = threadIdx.x;
    const int CH = (NSB + 63) / 64;
    int lo = lane * CH, hi = min(lo + CH, NSB);
    int s = 0;
    for (int i = lo; i < hi; i++) s += bsum[i];
    int x = s;
#pragma unroll
    for (int st = 1; st < 64; st <<= 1) { int v = __shfl_up(x, st); if (lane >= st) x += v; }
    int run = x - s;
    for (int i = lo; i < hi; i++) { bofs[i] = run; run += bsum[i]; }
    if (lane == 63) offs[NNODES] = run;
}

__global__ __launch_bounds__(256) void k_scan_final(const int* __restrict__ deg, const int* __restrict__ bofs,
                                                    int* __restrict__ offs, int* __restrict__ cur) {
    int b = blockIdx.x;
    int i = b * 256 + threadIdx.x;
    int v = (i < NNODES) ? deg[i] : 0;
    int lane = threadIdx.x & 63, wid = threadIdx.x >> 6;
    int x = v;
#pragma unroll
    for (int st = 1; st < 64; st <<= 1) { int t = __shfl_up(x, st); if (lane >= st) x += t; }
    __shared__ int ws[4];
    if (lane == 63) ws[wid] = x;
    __syncthreads();
    int wofs = 0;
#pragma unroll
    for (int w = 0; w < 4; w++) if (w < wid) wofs += ws[w];
    int excl = bofs[b] + wofs + x - v;
    if (i < NNODES) { offs[i] = excl; cur[i] = excl; }
}

__global__ void k_fill(const int* __restrict__ ei, const int* __restrict__ flag,
                       int* __restrict__ cur, int* __restrict__ csr) {
    int e = blockIdx.x * blockDim.x + threadIdx.x;
    if (e < NEDGES + NNODES) {
        int s, d;
        if (e < NEDGES) {
            int w = *flag;
            s = load_idx(ei, w, e);
            d = load_idx(ei, w, NEDGES + e);
        } else {
            s = e - NEDGES; d = s;
        }
        int pos = atomicAdd(&cur[d], 1);
        csr[pos] = s;
    }
}

// ---------------- per-head global max of src logits ----------------
template <int NH>
__global__ __launch_bounds__(256) void k_msrc(const float* __restrict__ src, uint* __restrict__ keys, int n) {
    float m = -3.0e38f;
    for (int i = blockIdx.x * 256 + threadIdx.x; i < n; i += gridDim.x * 256)
        m = fmaxf(m, src[i]);   // stride multiple of NH keeps head alignment
    __shared__ float red[256];
    red[threadIdx.x] = m;
    __syncthreads();
    for (int st = 128; st >= NH; st >>= 1) {
        if (threadIdx.x < st) red[threadIdx.x] = fmaxf(red[threadIdx.x], red[threadIdx.x + st]);
        __syncthreads();
    }
    if (threadIdx.x < NH) atomicMax(&keys[threadIdx.x], fkey(red[threadIdx.x]));
}

// ---------------- fp32 -> bf16 bulk convert ----------------
__global__ void k_f2bf(const float* __restrict__ in, ushort* __restrict__ out, int n4) {
    int i = blockIdx.x * blockDim.x + threadIdx.x;
    if (i < n4) {
        float4 v = ((const float4*)in)[i];
        ushort4 o = make_ushort4(f2bf(v.x), f2bf(v.y), f2bf(v.z), f2bf(v.w));
        ((ushort4*)out)[i] = o;
    }
}

// ---------------- W[512][512] fp32 -> Wt[512][512] bf16 transposed ----------------
__global__ __launch_bounds__(256) void k_transpose(const float* __restrict__ W, ushort* __restrict__ Wt) {
    __shared__ float tile[32][33];
    int bx = blockIdx.x, by = blockIdx.y;
    int tx = threadIdx.x & 31, ty = threadIdx.x >> 5;  // 32 x 8
#pragma unroll
    for (int i = 0; i < 4; i++)
        tile[ty + i * 8][tx] = W[(size_t)(by * 32 + ty + i * 8) * 512 + bx * 32 + tx];
    __syncthreads();
#pragma unroll
    for (int i = 0; i < 4; i++)
        Wt[(size_t)(bx * 32 + ty + i * 8) * 512 + by * 32 + tx] = f2bf(tile[tx][ty + i * 8]);
}

// ---------------- MFMA bf16 GEMM: C[M,512] = A[M,512] @ Bt^T; Bt is [N=512][K=512] ----------------
__global__ __launch_bounds__(256) void mfma_gemm(const ushort* __restrict__ A, const ushort* __restrict__ Bt,
                                                 ushort* __restrict__ C, int M) {
    __shared__ ushort As[64][40];    // +8 pad
    __shared__ ushort Bs[128][40];
    const int t = threadIdx.x;
    const int wid = t >> 6, lane = t & 63;
    const int wr = wid >> 1, wc = wid & 1;
    const int row0 = blockIdx.y * 64, col0 = blockIdx.x * 128;
    const int l15 = lane & 15, l4 = lane >> 4;
    f32x4 acc[2][4] = {};
    const int r = t >> 2, kc = (t & 3) * 8;
    for (int k0 = 0; k0 < 512; k0 += 32) {
        {
            int gr = row0 + r;
            bf16x8 v = {};
            if (gr < M) v = *(const bf16x8*)(A + (size_t)gr * 512 + k0 + kc);
            *(bf16x8*)&As[r][kc] = v;
            *(bf16x8*)&Bs[r][kc]      = *(const bf16x8*)(Bt + (size_t)(col0 + r) * 512 + k0 + kc);
            *(bf16x8*)&Bs[r + 64][kc] = *(const bf16x8*)(Bt + (size_t)(col0 + r + 64) * 512 + k0 + kc);
        }
        __syncthreads();
        bf16x8 af[2], bfr[4];
#pragma unroll
        for (int mr = 0; mr < 2; mr++)
            af[mr] = *(const bf16x8*)&As[wr * 32 + mr * 16 + l15][l4 * 8];
#pragma unroll
        for (int nr = 0; nr < 4; nr++)
            bfr[nr] = *(const bf16x8*)&Bs[wc * 64 + nr * 16 + l15][l4 * 8];
#pragma unroll
        for (int mr = 0; mr < 2; mr++)
#pragma unroll
            for (int nr = 0; nr < 4; nr++)
                acc[mr][nr] = __builtin_amdgcn_mfma_f32_16x16x32_bf16(af[mr], bfr[nr], acc[mr][nr], 0, 0, 0);
        __syncthreads();
    }
#pragma unroll
    for (int mr = 0; mr < 2; mr++) {
#pragma unroll
        for (int q = 0; q < 4; q++) {
            int gr = row0 + wr * 32 + mr * 16 + l4 * 4 + q;
            if (gr >= M) continue;
#pragma unroll
            for (int nr = 0; nr < 4; nr++) {
                int gc = col0 + wc * 64 + nr * 16 + l15;
                C[(size_t)gr * 512 + gc] = f2bf(acc[mr][nr][q]);
            }
        }
    }
}

// ---------------- fp32 GEMM (layer 3 only): A bf16, B fp32, C fp32 ----------------
__global__ __launch_bounds__(256) void bgemm64(const ushort* __restrict__ A, const float* __restrict__ B,
                                               float* __restrict__ C, int Mr, int Nc, int K) {
    __shared__ float As[16][68];
    __shared__ float Bs[16][68];
    int t = threadIdx.x;
    int tx = t & 15, ty = t >> 4;
    int row0 = blockIdx.y * 64, col0 = blockIdx.x * 64;
    float acc[4][4];
#pragma unroll
    for (int i = 0; i < 4; i++)
#pragma unroll
        for (int j = 0; j < 4; j++) acc[i][j] = 0.f;
    for (int k0 = 0; k0 < K; k0 += 16) {
        {
            int row = t >> 2, v = t & 3;
            int gr = row0 + row;
            float a0 = 0.f, a1 = 0.f, a2 = 0.f, a3 = 0.f;
            if (gr < Mr) {
                ushort4 a = *(const ushort4*)(A + (size_t)gr * K + k0 + v * 4);
                a0 = bf2f(a.x); a1 = bf2f(a.y); a2 = bf2f(a.z); a3 = bf2f(a.w);
            }
            As[v * 4 + 0][row] = a0;
            As[v * 4 + 1][row] = a1;
            As[v * 4 + 2][row] = a2;
            As[v * 4 + 3][row] = a3;
        }
        {
            int kr = t >> 4, c4 = t & 15;
#pragma unroll
            for (int j = 0; j < 4; j++) {
                int c = col0 + c4 * 4 + j;
                Bs[kr][c4 * 4 + j] = (c < Nc) ? B[(size_t)(k0 + kr) * Nc + c] : 0.f;
            }
        }
        __syncthreads();
#pragma unroll
        for (int kk = 0; kk < 16; kk++) {
            float4 a = *(const float4*)&As[kk][ty * 4];
            float4 b = *(const float4*)&Bs[kk][tx * 4];
            float av[4] = {a.x, a.y, a.z, a.w};
            float bv[4] = {b.x, b.y, b.z, b.w};
#pragma unroll
            for (int i = 0; i < 4; i++)
#pragma unroll
                for (int j = 0; j < 4; j++) acc[i][j] = fmaf(av[i], bv[j], acc[i][j]);
        }
        __syncthreads();
    }
#pragma unroll
    for (int i = 0; i < 4; i++) {
        int gr = row0 + ty * 4 + i;
        if (gr >= Mr) continue;
        for (int j = 0; j < 4; j++) {
            int gc = col0 + tx * 4 + j;
            if (gc < Nc) C[(size_t)gr * Nc + gc] = acc[i][j];
        }
    }
}

// ---------------- per-node attention logits, 8 heads (h bf16) ----------------
__global__ __launch_bounds__(256) void k_alpha8(const ushort* __restrict__ h, const float* __restrict__ att_s,
                                                const float* __restrict__ att_d, float* __restrict__ asrc,
                                                float* __restrict__ adst) {
    int gw = (blockIdx.x * 256 + threadIdx.x) >> 6;
    int lane = threadIdx.x & 63;
    if (gw >= NNODES * NHEADS) return;
    int n = gw >> 3, hh = gw & 7;
    float v = bf2f(h[(size_t)n * FINCH + hh * HIDC + lane]);
    float s1 = v * att_s[hh * HIDC + lane];
    float s2 = v * att_d[hh * HIDC + lane];
#pragma unroll
    for (int m = 32; m > 0; m >>= 1) { s1 += __shfl_xor(s1, m); s2 += __shfl_xor(s2, m); }
    if (lane == 0) { asrc[n * 8 + hh] = s1; adst[n * 8 + hh] = s2; }
}

__global__ __launch_bounds__(256) void k_alpha1(const float* __restrict__ h, const float* __restrict__ att_s,
                                                const float* __restrict__ att_d, float* __restrict__ asrc,
                                                float* __restrict__ adst) {
    int gw = (blockIdx.x * 256 + threadIdx.x) >> 6;
    int lane = threadIdx.x & 63;
    if (gw >= NNODES) return;
    float s1 = 0.f, s2 = 0.f;
    if (lane < OUTC) {
        float v = h[(size_t)gw * OUTC + lane];
        s1 = v * att_s[lane];
        s2 = v * att_d[lane];
    }
#pragma unroll
    for (int m = 32; m > 0; m >>= 1) { s1 += __shfl_xor(s1, m); s2 += __shfl_xor(s2, m); }
    if (lane == 0) { asrc[gw] = s1; adst[gw] = s2; }
}

// ---------------- aggregation v3: one wave per node, global-max softmax, pipelined gather ----------------
template <bool DO_ELU>
__global__ __launch_bounds__(256) void agg_v3(const ushort* __restrict__ h, const float* __restrict__ asrc,
                                              const float* __restrict__ adst, const int* __restrict__ offs,
                                              const int* __restrict__ csr, const float* __restrict__ bias,
                                              const uint* __restrict__ mkeys, ushort* __restrict__ out) {
    const int wid = threadIdx.x >> 6, lane = threadIdx.x & 63;
    const int n = blockIdx.x * 4 + wid;
    if (n >= NNODES) return;
    const int beg = offs[n], deg = offs[n + 1] - beg;
    const int h8 = lane & 7;   // head (stats layout)
    const int es = lane >> 3;  // edge slot
    const float ad_s = adst[n * 8 + h8];
    const float m8 = leaky(fdec(mkeys[h8]) + ad_s);   // per-(n,h) upper bound on e

    // single stats pass: sum of exp(e - m8)
    float ss = 0.f;
    for (int i = es; i < deg; i += 8) {
        int s = csr[beg + i];
        ss += expf(leaky(asrc[s * 8 + h8] + ad_s) - m8);
    }
    ss += __shfl_xor(ss, 8);
    ss += __shfl_xor(ss, 16);
    ss += __shfl_xor(ss, 32);

    // remap: lane owns channels lane*8.., head hc = lane>>3
    const int hc = lane >> 3;
    const float mc  = __shfl(m8, hc);
    const float rsc = 1.f / __shfl(ss, hc);
    const float adc = __shfl(ad_s, hc);

    float acc[8] = {0.f, 0.f, 0.f, 0.f, 0.f, 0.f, 0.f, 0.f};
    for (int base = 0; base < deg; base += 64) {
        // 64-wide coalesced csr prefetch, broadcast via shfl
        int sv = (base + lane < deg) ? csr[beg + base + lane] : 0;
        int cnt = min(64, deg - base);
        int j = 0;
        for (; j + 2 <= cnt; j += 2) {
            int s0 = __shfl(sv, j), s1 = __shfl(sv, j + 1);
            float a0 = asrc[s0 * 8 + hc], a1 = asrc[s1 * 8 + hc];
            bf16x8 h0 = *(const bf16x8*)(h + (size_t)s0 * FINCH + lane * 8);
            bf16x8 h1 = *(const bf16x8*)(h + (size_t)s1 * FINCH + lane * 8);
            float w0 = expf(leaky(a0 + adc) - mc) * rsc;
            float w1 = expf(leaky(a1 + adc) - mc) * rsc;
#pragma unroll
            for (int c = 0; c < 8; c++) acc[c] = fmaf(bf2f((ushort)h0[c]), w0, acc[c]);
#pragma unroll
            for (int c = 0; c < 8; c++) acc[c] = fmaf(bf2f((ushort)h1[c]), w1, acc[c]);
        }
        if (j < cnt) {
            int s0 = __shfl(sv, j);
            float a0 = asrc[s0 * 8 + hc];
            bf16x8 h0 = *(const bf16x8*)(h + (size_t)s0 * FINCH + lane * 8);
            float w0 = expf(leaky(a0 + adc) - mc) * rsc;
#pragma unroll
            for (int c = 0; c < 8; c++) acc[c] = fmaf(bf2f((ushort)h0[c]), w0, acc[c]);
        }
    }
    ushort o[8];
#pragma unroll
    for (int c = 0; c < 8; c++) {
        float v = acc[c] + bias[lane * 8 + c];
        if (DO_ELU) v = v > 0.f ? v : expf(v) - 1.f;
        o[c] = f2bf(v);
    }
    *(bf16x8*)(out + (size_t)n * FINCH + lane * 8) = *(bf16x8*)o;
}

// ---------------- layer-3: one wave per node; agg + bias + log_softmax (fp32 out) ----------------
__global__ __launch_bounds__(64) void agg_out(const float* __restrict__ h3, const float* __restrict__ asrc,
                                              const float* __restrict__ adst, const int* __restrict__ offs,
                                              const int* __restrict__ csr, const float* __restrict__ bias,
                                              const uint* __restrict__ mkeys, float* __restrict__ out) {
    const int n = blockIdx.x, lane = threadIdx.x;
    const int beg = offs[n], deg = offs[n + 1] - beg;
    const float ad = adst[n];
    const float m = leaky(fdec(mkeys[0]) + ad);

    float ss = 0.f;
    for (int i = lane; i < deg; i += 64) ss += expf(leaky(asrc[csr[beg + i]] + ad) - m);
#pragma unroll
    for (int w = 32; w > 0; w >>= 1) ss += __shfl_xor(ss, w);
    float rs = 1.f / ss;

    float acc = 0.f;
    for (int base = 0; base < deg; base += 64) {
        int sv = (base + lane < deg) ? csr[beg + base + lane] : 0;
        int cnt = min(64, deg - base);
        int j = 0;
        for (; j + 2 <= cnt; j += 2) {
            int s0 = __shfl(sv, j), s1 = __shfl(sv, j + 1);
            float a0 = asrc[s0], a1 = asrc[s1];
            float v0 = (lane < OUTC) ? h3[(size_t)s0 * OUTC + lane] : 0.f;
            float v1 = (lane < OUTC) ? h3[(size_t)s1 * OUTC + lane] : 0.f;
            float w0 = expf(leaky(a0 + ad) - m) * rs;
            float w1 = expf(leaky(a1 + ad) - m) * rs;
            acc = fmaf(v0, w0, acc);
            acc = fmaf(v1, w1, acc);
        }
        if (j < cnt) {
            int s0 = __shfl(sv, j);
            float w0 = expf(leaky(asrc[s0] + ad) - m) * rs;
            float v0 = (lane < OUTC) ? h3[(size_t)s0 * OUTC + lane] : 0.f;
            acc = fmaf(v0, w0, acc);
        }
    }
    float v = (lane < OUTC) ? acc + bias[lane] : -1e30f;
    float mx = v;
#pragma unroll
    for (int w = 32; w > 0; w >>= 1) mx = fmaxf(mx, __shfl_xor(mx, w));
    float ex = (lane < OUTC) ? expf(v - mx) : 0.f;
    float se = ex;
#pragma unroll
    for (int w = 32; w > 0; w >>= 1) se += __shfl_xor(se, w);
    if (lane < OUTC) out[(size_t)n * OUTC + lane] = v - mx - logf(se);
}

extern "C" void kernel_launch(void* const* d_in, const int* in_sizes, int n_in,
                              void* d_out, int out_size, void* d_ws, size_t ws_size,
                              hipStream_t stream) {
    const float* x   = (const float*)d_in[0];
    const int*   ei  = (const int*)d_in[1];
    const float* W1  = (const float*)d_in[2];
    const float* as1 = (const float*)d_in[3];
    const float* ad1 = (const float*)d_in[4];
    const float* b1  = (const float*)d_in[5];
    const float* W2  = (const float*)d_in[6];
    const float* as2 = (const float*)d_in[7];
    const float* ad2 = (const float*)d_in[8];
    const float* b2  = (const float*)d_in[9];
    const float* W3  = (const float*)d_in[10];
    const float* as3 = (const float*)d_in[11];
    const float* ad3 = (const float*)d_in[12];
    const float* b3  = (const float*)d_in[13];
    float* out = (float*)d_out;

    // workspace (~111 MB; <= proven-safe 118 MB)
    char* p = (char*)d_ws;
    ushort* bufA = (ushort*)p; p += (size_t)NNODES * FINCH * 2;   // h1/h2 bf16; h3 fp32 later
    ushort* bufB = (ushort*)p; p += (size_t)NNODES * FINCH * 2;   // x_bf16, then x2/x3 bf16
    float* asrc = (float*)p; p += (size_t)NNODES * 8 * 4;
    float* adst = (float*)p; p += (size_t)NNODES * 8 * 4;
    int* flag = (int*)p; p += 16;
    uint* mkeys = (uint*)p; p += 128;   // slots: 0..7 L1, 8..15 L2, 16 L3
    int* deg  = (int*)p; p += (size_t)NNODES * 4;
    int* offs = (int*)p; p += (size_t)(NNODES + 1) * 4;
    int* cur  = (int*)p; p += (size_t)NNODES * 4;
    int* csr  = (int*)p; p += (size_t)(NEDGES + NNODES) * 4;
    ushort* Wt1 = (ushort*)p; p += (size_t)512 * 512 * 2;
    ushort* Wt2 = (ushort*)p; p += (size_t)512 * 512 * 2;
    int* bsum = (int*)p; p += (size_t)NSB * 4;
    int* bofs = (int*)p; p += (size_t)NSB * 4;
    float* h3 = (float*)bufA;
    float* asc3 = asrc;
    float* adc3 = adst;

    // graph build (CSR by dst, with self-loops)
    k_detect<<<1, 64, 0, stream>>>(ei, flag, mkeys);
    k_init_deg<<<(NNODES + 255) / 256, 256, 0, stream>>>(deg);
    k_count<<<(NEDGES + 255) / 256, 256, 0, stream>>>(ei, flag, deg);
    k_bsum<<<NSB, 256, 0, stream>>>(deg, bsum);
    k_bscan<<<1, 64, 0, stream>>>(bsum, bofs, offs);
    k_scan_final<<<NSB, 256, 0, stream>>>(deg, bofs, offs, cur);
    k_fill<<<(NEDGES + NNODES + 255) / 256, 256, 0, stream>>>(ei, flag, cur, csr);

    // precision prep: x -> bf16 (bufB), W1/W2 -> bf16 transposed [N][K]
    {
        int n4 = NNODES * FINCH / 4;
        k_f2bf<<<(n4 + 255) / 256, 256, 0, stream>>>(x, bufB, n4);
        dim3 gt(16, 16);
        k_transpose<<<gt, 256, 0, stream>>>(W1, Wt1);
        k_transpose<<<gt, 256, 0, stream>>>(W2, Wt2);
    }

    dim3 gg(4, (NNODES + 63) / 64);
    int gagg = (NNODES + 3) / 4;
    // layer 1
    mfma_gemm<<<gg, 256, 0, stream>>>(bufB, Wt1, bufA, NNODES);
    k_alpha8<<<(NNODES * 8 * 64) / 256, 256, 0, stream>>>(bufA, as1, ad1, asrc, adst);
    k_msrc<8><<<128, 256, 0, stream>>>(asrc, mkeys, NNODES * 8);
    agg_v3<true><<<gagg, 256, 0, stream>>>(bufA, asrc, adst, offs, csr, b1, mkeys, bufB);
    // layer 2
    mfma_gemm<<<gg, 256, 0, stream>>>(bufB, Wt2, bufA, NNODES);
    k_alpha8<<<(NNODES * 8 * 64) / 256, 256, 0, stream>>>(bufA, as2, ad2, asrc, adst);
    k_msrc<8><<<128, 256, 0, stream>>>(asrc, mkeys + 8, NNODES * 8);
    agg_v3<true><<<gagg, 256, 0, stream>>>(bufA, asrc, adst, offs, csr, b2, mkeys + 8, bufB);
    // layer 3 (+ fused log_softmax)
    dim3 g3(1, (NNODES + 63) / 64);
    bgemm64<<<g3, 256, 0, stream>>>(bufB, W3, h3, NNODES, OUTC, 512);
    k_alpha1<<<(NNODES * 64 + 255) / 256, 256, 0, stream>>>(h3, as3, ad3, asc3, adc3);
    k_msrc<1><<<128, 256, 0, stream>>>(asc3, mkeys + 16, NNODES);
    agg_out<<<NNODES, 64, 0, stream>>>(h3, asc3, adc3, offs, csr, b3, mkeys + 16, out);
}

// Round 8
// 749.429 us; speedup vs baseline: 2.8713x; 1.0275x over previous
//
#include <hip/hip_runtime.h>
#include <math.h>

#define NNODES 50000
#define NEDGES 800000
#define FINCH 512
#define HIDC 64
#define NHEADS 8
#define OUTC 40
#define NSLOPE 0.2f
#define NSB ((NNODES + 255) / 256)

typedef unsigned short ushort;
typedef unsigned int uint;
typedef __attribute__((ext_vector_type(8))) short bf16x8;
typedef __attribute__((ext_vector_type(4))) float f32x4;

static __device__ __forceinline__ float leaky(float e) { return e > 0.f ? e : NSLOPE * e; }

static __device__ __forceinline__ float bf2f(ushort u) {
    union { unsigned int i; float f; } c; c.i = ((unsigned int)u) << 16; return c.f;
}
static __device__ __forceinline__ ushort f2bf(float f) {
    union { float f; unsigned int i; } c; c.f = f;
    unsigned int r = c.i + 0x7FFF + ((c.i >> 16) & 1);  // round-nearest-even
    return (ushort)(r >> 16);
}
// order-preserving float<->uint key (for atomicMax on floats)
static __device__ __forceinline__ uint fkey(float f) {
    uint u = __float_as_uint(f);
    return (u & 0x80000000u) ? ~u : (u | 0x80000000u);
}
static __device__ __forceinline__ float fdec(uint k) {
    return __uint_as_float((k & 0x80000000u) ? (k & 0x7fffffffu) : ~k);
}

// async global->LDS 16B (wave-uniform LDS base + lane*16; per-lane global src)
static __device__ __forceinline__ void gload16(const ushort* g, ushort* l) {
    __builtin_amdgcn_global_load_lds((const __attribute__((address_space(1))) void*)g,
                                     (__attribute__((address_space(3))) void*)l, 16, 0, 0);
}

// ---------------- edge dtype detect + key init ----------------
__global__ __launch_bounds__(64) void k_detect(const int* __restrict__ ei, int* __restrict__ flag,
                                               uint* __restrict__ keys) {
    int lane = threadIdx.x;
    if (lane < 17) keys[lane] = fkey(-3.0e38f);
    int v = ei[2 * lane + 1];
    unsigned long long b = __ballot(v != 0);
    if (lane == 0) *flag = (b == 0ULL) ? 1 : 0;
}

static __device__ __forceinline__ int load_idx(const int* ei, int wide, int pos) {
    int v = wide ? ei[2 * (long long)pos] : ei[pos];
    v = v < 0 ? 0 : (v >= NNODES ? NNODES - 1 : v);
    return v;
}

// ---------------- graph build ----------------
__global__ void k_init_deg(int* __restrict__ deg) {
    int i = blockIdx.x * blockDim.x + threadIdx.x;
    if (i < NNODES) deg[i] = 1;  // self-loop
}

__global__ void k_count(const int* __restrict__ ei, const int* __restrict__ flag, int* __restrict__ deg) {
    int e = blockIdx.x * blockDim.x + threadIdx.x;
    if (e < NEDGES) {
        int d = load_idx(ei, *flag, NEDGES + e);
        atomicAdd(&deg[d], 1);
    }
}

__global__ __launch_bounds__(256) void k_bsum(const int* __restrict__ deg, int* __restrict__ bsum) {
    int i = blockIdx.x * 256 + threadIdx.x;
    int v = (i < NNODES) ? deg[i] : 0;
#pragma unroll
    for (int m = 32; m > 0; m >>= 1) v += __shfl_xor(v, m);
    __shared__ int ws[4];
    int wid = threadIdx.x >> 6, lane = threadIdx.x & 63;
    if (lane == 0) ws[wid] = v;
    __syncthreads();
    if (threadIdx.x == 0) bsum[blockIdx.x] = ws[0] + ws[1] + ws[2] + ws[3];
}

__global__ __launch_bounds__(64) void k_bscan(const int* __restrict__ bsum, int* __restrict__ bofs,
                                              int* __restrict__ offs) {
    const int lane = threadIdx.x;
    const int CH = (NSB + 63) / 64;
    int lo = lane * CH, hi = min(lo + CH, NSB);
    int s = 0;
    for (int i = lo; i < hi; i++) s += bsum[i];
    int x = s;
#pragma unroll
    for (int st = 1; st < 64; st <<= 1) { int v = __shfl_up(x, st); if (lane >= st) x += v; }
    int run = x - s;
    for (int i = lo; i < hi; i++) { bofs[i] = run; run += bsum[i]; }
    if (lane == 63) offs[NNODES] = run;
}

__global__ __launch_bounds__(256) void k_scan_final(const int* __restrict__ deg, const int* __restrict__ bofs,
                                                    int* __restrict__ offs, int* __restrict__ cur) {
    int b = blockIdx.x;
    int i = b * 256 + threadIdx.x;
    int v = (i < NNODES) ? deg[i] : 0;
    int lane = threadIdx.x & 63, wid = threadIdx.x >> 6;
    int x = v;
#pragma unroll
    for (int st = 1; st < 64; st <<= 1) { int t = __shfl_up(x, st); if (lane >= st) x += t; }
    __shared__ int ws[4];
    if (lane == 63) ws[wid] = x;
    __syncthreads();
    int wofs = 0;
#pragma unroll
    for (int w = 0; w < 4; w++) if (w < wid) wofs += ws[w];
    int excl = bofs[b] + wofs + x - v;
    if (i < NNODES) { offs[i] = excl; cur[i] = excl; }
}

__global__ void k_fill(const int* __restrict__ ei, const int* __restrict__ flag,
                       int* __restrict__ cur, int* __restrict__ csr) {
    int e = blockIdx.x * blockDim.x + threadIdx.x;
    if (e < NEDGES + NNODES) {
        int s, d;
        if (e < NEDGES) {
            int w = *flag;
            s = load_idx(ei, w, e);
            d = load_idx(ei, w, NEDGES + e);
        } else {
            s = e - NEDGES; d = s;
        }
        int pos = atomicAdd(&cur[d], 1);
        csr[pos] = s;
    }
}

// ---------------- per-head global max of src logits ----------------
template <int NH>
__global__ __launch_bounds__(256) void k_msrc(const float* __restrict__ src, uint* __restrict__ keys, int n) {
    float m = -3.0e38f;
    for (int i = blockIdx.x * 256 + threadIdx.x; i < n; i += gridDim.x * 256)
        m = fmaxf(m, src[i]);   // stride multiple of NH keeps head alignment
    __shared__ float red[256];
    red[threadIdx.x] = m;
    __syncthreads();
    for (int st = 128; st >= NH; st >>= 1) {
        if (threadIdx.x < st) red[threadIdx.x] = fmaxf(red[threadIdx.x], red[threadIdx.x + st]);
        __syncthreads();
    }
    if (threadIdx.x < NH) atomicMax(&keys[threadIdx.x], fkey(red[threadIdx.x]));
}

// ---------------- fp32 -> bf16 bulk convert ----------------
__global__ void k_f2bf(const float* __restrict__ in, ushort* __restrict__ out, int n4) {
    int i = blockIdx.x * blockDim.x + threadIdx.x;
    if (i < n4) {
        float4 v = ((const float4*)in)[i];
        ushort4 o = make_ushort4(f2bf(v.x), f2bf(v.y), f2bf(v.z), f2bf(v.w));
        ((ushort4*)out)[i] = o;
    }
}

// ---------------- W[512][512] fp32 -> Wt[512][512] bf16 transposed ----------------
__global__ __launch_bounds__(256) void k_transpose(const float* __restrict__ W, ushort* __restrict__ Wt) {
    __shared__ float tile[32][33];
    int bx = blockIdx.x, by = blockIdx.y;
    int tx = threadIdx.x & 31, ty = threadIdx.x >> 5;  // 32 x 8
#pragma unroll
    for (int i = 0; i < 4; i++)
        tile[ty + i * 8][tx] = W[(size_t)(by * 32 + ty + i * 8) * 512 + bx * 32 + tx];
    __syncthreads();
#pragma unroll
    for (int i = 0; i < 4; i++)
        Wt[(size_t)(bx * 32 + ty + i * 8) * 512 + by * 32 + tx] = f2bf(tile[tx][ty + i * 8]);
}

// ---------------- MFMA bf16 GEMM v2 (m97-style): 128x128 tile, BK=32, 8 waves ----------------
// C[M,512] = A[M,512] @ Bt^T, Bt = [N=512][K=512]. global_load_lds staging,
// linear LDS rows of 64B with chunk-XOR swizzle (kb' = kb ^ ((row>>1)&3)).
__global__ __launch_bounds__(512) void mfma_gemm2(const ushort* __restrict__ A, const ushort* __restrict__ Bt,
                                                  ushort* __restrict__ C, int M) {
    __shared__ ushort Abuf[128 * 32];   // 128 rows x 64B
    __shared__ ushort Bbuf[128 * 32];
    const int t = threadIdx.x;
    const int wid = t >> 6, lane = t & 63;
    const int wr = wid >> 1, wc = wid & 1;          // 4 x 2 waves
    const int row0 = blockIdx.y * 128, col0 = blockIdx.x * 128;
    const int l15 = lane & 15, l4 = lane >> 4;
    const int arow = t >> 2, kb = t & 3;            // staging coords
    const int swz = (arow >> 1) & 3;
    const int ra = min(row0 + arow, M - 1);         // clamp (dup rows, stores guarded)
    const ushort* gA = A + (size_t)ra * 512 + ((kb ^ swz) << 3);
    const ushort* gB = Bt + (size_t)(col0 + arow) * 512 + ((kb ^ swz) << 3);
    ushort* lA = &Abuf[wid * 512];                  // wave-uniform base; lane*16B implicit
    ushort* lB = &Bbuf[wid * 512];
    f32x4 acc[2][4] = {};
    for (int k0 = 0; k0 < 512; k0 += 32) {
        gload16(gA + k0, lA);
        gload16(gB + k0, lB);
        __syncthreads();   // drain vmcnt -> staged data visible
        bf16x8 af[2], bfr[4];
#pragma unroll
        for (int mr = 0; mr < 2; mr++) {
            int r = wr * 32 + mr * 16 + l15;
            af[mr] = *(const bf16x8*)&Abuf[r * 32 + ((l4 ^ ((r >> 1) & 3)) << 3)];
        }
#pragma unroll
        for (int nr = 0; nr < 4; nr++) {
            int c = wc * 64 + nr * 16 + l15;
            bfr[nr] = *(const bf16x8*)&Bbuf[c * 32 + ((l4 ^ ((c >> 1) & 3)) << 3)];
        }
#pragma unroll
        for (int mr = 0; mr < 2; mr++)
#pragma unroll
            for (int nr = 0; nr < 4; nr++)
                acc[mr][nr] = __builtin_amdgcn_mfma_f32_16x16x32_bf16(af[mr], bfr[nr], acc[mr][nr], 0, 0, 0);
        __syncthreads();   // protect LDS before next-iter overwrite
    }
#pragma unroll
    for (int mr = 0; mr < 2; mr++) {
#pragma unroll
        for (int q = 0; q < 4; q++) {
            int gr = row0 + wr * 32 + mr * 16 + l4 * 4 + q;
            if (gr >= M) continue;
#pragma unroll
            for (int nr = 0; nr < 4; nr++) {
                int gc = col0 + wc * 64 + nr * 16 + l15;
                C[(size_t)gr * 512 + gc] = f2bf(acc[mr][nr][q]);
            }
        }
    }
}

// ---------------- fp32 GEMM (layer 3 only): A bf16, B fp32, C fp32 ----------------
__global__ __launch_bounds__(256) void bgemm64(const ushort* __restrict__ A, const float* __restrict__ B,
                                               float* __restrict__ C, int Mr, int Nc, int K) {
    __shared__ float As[16][68];
    __shared__ float Bs[16][68];
    int t = threadIdx.x;
    int tx = t & 15, ty = t >> 4;
    int row0 = blockIdx.y * 64, col0 = blockIdx.x * 64;
    float acc[4][4];
#pragma unroll
    for (int i = 0; i < 4; i++)
#pragma unroll
        for (int j = 0; j < 4; j++) acc[i][j] = 0.f;
    for (int k0 = 0; k0 < K; k0 += 16) {
        {
            int row = t >> 2, v = t & 3;
            int gr = row0 + row;
            float a0 = 0.f, a1 = 0.f, a2 = 0.f, a3 = 0.f;
            if (gr < Mr) {
                ushort4 a = *(const ushort4*)(A + (size_t)gr * K + k0 + v * 4);
                a0 = bf2f(a.x); a1 = bf2f(a.y); a2 = bf2f(a.z); a3 = bf2f(a.w);
            }
            As[v * 4 + 0][row] = a0;
            As[v * 4 + 1][row] = a1;
            As[v * 4 + 2][row] = a2;
            As[v * 4 + 3][row] = a3;
        }
        {
            int kr = t >> 4, c4 = t & 15;
#pragma unroll
            for (int j = 0; j < 4; j++) {
                int c = col0 + c4 * 4 + j;
                Bs[kr][c4 * 4 + j] = (c < Nc) ? B[(size_t)(k0 + kr) * Nc + c] : 0.f;
            }
        }
        __syncthreads();
#pragma unroll
        for (int kk = 0; kk < 16; kk++) {
            float4 a = *(const float4*)&As[kk][ty * 4];
            float4 b = *(const float4*)&Bs[kk][tx * 4];
            float av[4] = {a.x, a.y, a.z, a.w};
            float bv[4] = {b.x, b.y, b.z, b.w};
#pragma unroll
            for (int i = 0; i < 4; i++)
#pragma unroll
                for (int j = 0; j < 4; j++) acc[i][j] = fmaf(av[i], bv[j], acc[i][j]);
        }
        __syncthreads();
    }
#pragma unroll
    for (int i = 0; i < 4; i++) {
        int gr = row0 + ty * 4 + i;
        if (gr >= Mr) continue;
        for (int j = 0; j < 4; j++) {
            int gc = col0 + tx * 4 + j;
            if (gc < Nc) C[(size_t)gr * Nc + gc] = acc[i][j];
        }
    }
}

// ---------------- per-node attention logits, 8 heads (h bf16) ----------------
__global__ __launch_bounds__(256) void k_alpha8(const ushort* __restrict__ h, const float* __restrict__ att_s,
                                                const float* __restrict__ att_d, float* __restrict__ asrc,
                                                float* __restrict__ adst) {
    int gw = (blockIdx.x * 256 + threadIdx.x) >> 6;
    int lane = threadIdx.x & 63;
    if (gw >= NNODES * NHEADS) return;
    int n = gw >> 3, hh = gw & 7;
    float v = bf2f(h[(size_t)n * FINCH + hh * HIDC + lane]);
    float s1 = v * att_s[hh * HIDC + lane];
    float s2 = v * att_d[hh * HIDC + lane];
#pragma unroll
    for (int m = 32; m > 0; m >>= 1) { s1 += __shfl_xor(s1, m); s2 += __shfl_xor(s2, m); }
    if (lane == 0) { asrc[n * 8 + hh] = s1; adst[n * 8 + hh] = s2; }
}

__global__ __launch_bounds__(256) void k_alpha1(const float* __restrict__ h, const float* __restrict__ att_s,
                                                const float* __restrict__ att_d, float* __restrict__ asrc,
                                                float* __restrict__ adst) {
    int gw = (blockIdx.x * 256 + threadIdx.x) >> 6;
    int lane = threadIdx.x & 63;
    if (gw >= NNODES) return;
    float s1 = 0.f, s2 = 0.f;
    if (lane < OUTC) {
        float v = h[(size_t)gw * OUTC + lane];
        s1 = v * att_s[lane];
        s2 = v * att_d[lane];
    }
#pragma unroll
    for (int m = 32; m > 0; m >>= 1) { s1 += __shfl_xor(s1, m); s2 += __shfl_xor(s2, m); }
    if (lane == 0) { asrc[gw] = s1; adst[gw] = s2; }
}

// ---------------- aggregation v4: weights computed once in stats layout, shfl-broadcast ----------------
template <bool DO_ELU>
__global__ __launch_bounds__(256) void agg_v4(const ushort* __restrict__ h, const float* __restrict__ asrc,
                                              const float* __restrict__ adst, const int* __restrict__ offs,
                                              const int* __restrict__ csr, const float* __restrict__ bias,
                                              const uint* __restrict__ mkeys, ushort* __restrict__ out) {
    const int wid = threadIdx.x >> 6, lane = threadIdx.x & 63;
    const int n = blockIdx.x * 4 + wid;
    if (n >= NNODES) return;
    const int beg = offs[n], deg = offs[n + 1] - beg;
    const int h8 = lane & 7;   // head (stats layout)
    const int es = lane >> 3;  // edge slot
    const float ad_s = adst[n * 8 + h8];
    const float m8 = leaky(fdec(mkeys[h8]) + ad_s);   // per-(n,h) upper bound on e

    // single stats pass: sum of exp(e - m8)
    float ss = 0.f;
    for (int i = es; i < deg; i += 8) {
        int s = csr[beg + i];
        ss += expf(leaky(asrc[s * 8 + h8] + ad_s) - m8);
    }
    ss += __shfl_xor(ss, 8);
    ss += __shfl_xor(ss, 16);
    ss += __shfl_xor(ss, 32);
    const float rs8 = 1.f / ss;   // lane's own head h8

    const int hc = lane >> 3;     // consuming head (channel layout: lane owns ch lane*8..)
    float acc[8] = {0.f, 0.f, 0.f, 0.f, 0.f, 0.f, 0.f, 0.f};
    int base = 0;
    for (; base + 8 <= deg; base += 8) {
        int sv = csr[beg + base + es];
        float wv = expf(leaky(asrc[sv * 8 + h8] + ad_s) - m8) * rs8;  // w(edge base+es, head h8)
#pragma unroll
        for (int j = 0; j < 8; j++) {
            int src = (j << 3) | hc;
            float w = __shfl(wv, src);
            int s = __shfl(sv, src);
            bf16x8 hv = *(const bf16x8*)(h + (size_t)s * FINCH + lane * 8);
#pragma unroll
            for (int c = 0; c < 8; c++) acc[c] = fmaf(bf2f((ushort)hv[c]), w, acc[c]);
        }
    }
    if (base < deg) {
        int e = base + es;
        int sv = csr[beg + min(e, deg - 1)];
        float wv = (e < deg) ? expf(leaky(asrc[sv * 8 + h8] + ad_s) - m8) * rs8 : 0.f;
        int cnt = deg - base;
        for (int j = 0; j < cnt; j++) {
            int src = (j << 3) | hc;
            float w = __shfl(wv, src);
            int s = __shfl(sv, src);
            bf16x8 hv = *(const bf16x8*)(h + (size_t)s * FINCH + lane * 8);
#pragma unroll
            for (int c = 0; c < 8; c++) acc[c] = fmaf(bf2f((ushort)hv[c]), w, acc[c]);
        }
    }
    ushort o[8];
#pragma unroll
    for (int c = 0; c < 8; c++) {
        float v = acc[c] + bias[lane * 8 + c];
        if (DO_ELU) v = v > 0.f ? v : expf(v) - 1.f;
        o[c] = f2bf(v);
    }
    *(bf16x8*)(out + (size_t)n * FINCH + lane * 8) = *(bf16x8*)o;
}

// ---------------- layer-3: one wave per node; agg + bias + log_softmax (fp32 out) ----------------
__global__ __launch_bounds__(64) void agg_out(const float* __restrict__ h3, const float* __restrict__ asrc,
                                              const float* __restrict__ adst, const int* __restrict__ offs,
                                              const int* __restrict__ csr, const float* __restrict__ bias,
                                              const uint* __restrict__ mkeys, float* __restrict__ out) {
    const int n = blockIdx.x, lane = threadIdx.x;
    const int beg = offs[n], deg = offs[n + 1] - beg;
    const float ad = adst[n];
    const float m = leaky(fdec(mkeys[0]) + ad);

    float ss = 0.f;
    for (int i = lane; i < deg; i += 64) ss += expf(leaky(asrc[csr[beg + i]] + ad) - m);
#pragma unroll
    for (int w = 32; w > 0; w >>= 1) ss += __shfl_xor(ss, w);
    float rs = 1.f / ss;

    float acc = 0.f;
    for (int base = 0; base < deg; base += 64) {
        int sv = (base + lane < deg) ? csr[beg + base + lane] : 0;
        int cnt = min(64, deg - base);
        int j = 0;
        for (; j + 2 <= cnt; j += 2) {
            int s0 = __shfl(sv, j), s1 = __shfl(sv, j + 1);
            float a0 = asrc[s0], a1 = asrc[s1];
            float v0 = (lane < OUTC) ? h3[(size_t)s0 * OUTC + lane] : 0.f;
            float v1 = (lane < OUTC) ? h3[(size_t)s1 * OUTC + lane] : 0.f;
            float w0 = expf(leaky(a0 + ad) - m) * rs;
            float w1 = expf(leaky(a1 + ad) - m) * rs;
            acc = fmaf(v0, w0, acc);
            acc = fmaf(v1, w1, acc);
        }
        if (j < cnt) {
            int s0 = __shfl(sv, j);
            float w0 = expf(leaky(asrc[s0] + ad) - m) * rs;
            float v0 = (lane < OUTC) ? h3[(size_t)s0 * OUTC + lane] : 0.f;
            acc = fmaf(v0, w0, acc);
        }
    }
    float v = (lane < OUTC) ? acc + bias[lane] : -1e30f;
    float mx = v;
#pragma unroll
    for (int w = 32; w > 0; w >>= 1) mx = fmaxf(mx, __shfl_xor(mx, w));
    float ex = (lane < OUTC) ? expf(v - mx) : 0.f;
    float se = ex;
#pragma unroll
    for (int w = 32; w > 0; w >>= 1) se += __shfl_xor(se, w);
    if (lane < OUTC) out[(size_t)n * OUTC + lane] = v - mx - logf(se);
}

extern "C" void kernel_launch(void* const* d_in, const int* in_sizes, int n_in,
                              void* d_out, int out_size, void* d_ws, size_t ws_size,
                              hipStream_t stream) {
    const float* x   = (const float*)d_in[0];
    const int*   ei  = (const int*)d_in[1];
    const float* W1  = (const float*)d_in[2];
    const float* as1 = (const float*)d_in[3];
    const float* ad1 = (const float*)d_in[4];
    const float* b1  = (const float*)d_in[5];
    const float* W2  = (const float*)d_in[6];
    const float* as2 = (const float*)d_in[7];
    const float* ad2 = (const float*)d_in[8];
    const float* b2  = (const float*)d_in[9];
    const float* W3  = (const float*)d_in[10];
    const float* as3 = (const float*)d_in[11];
    const float* ad3 = (const float*)d_in[12];
    const float* b3  = (const float*)d_in[13];
    float* out = (float*)d_out;

    // workspace (~111 MB; <= proven-safe 118 MB)
    char* p = (char*)d_ws;
    ushort* bufA = (ushort*)p; p += (size_t)NNODES * FINCH * 2;   // h1/h2 bf16; h3 fp32 later
    ushort* bufB = (ushort*)p; p += (size_t)NNODES * FINCH * 2;   // x_bf16, then x2/x3 bf16
    float* asrc = (float*)p; p += (size_t)NNODES * 8 * 4;
    float* adst = (float*)p; p += (size_t)NNODES * 8 * 4;
    int* flag = (int*)p; p += 16;
    uint* mkeys = (uint*)p; p += 128;   // slots: 0..7 L1, 8..15 L2, 16 L3
    int* deg  = (int*)p; p += (size_t)NNODES * 4;
    int* offs = (int*)p; p += (size_t)(NNODES + 1) * 4;
    int* cur  = (int*)p; p += (size_t)NNODES * 4;
    int* csr  = (int*)p; p += (size_t)(NEDGES + NNODES) * 4;
    ushort* Wt1 = (ushort*)p; p += (size_t)512 * 512 * 2;
    ushort* Wt2 = (ushort*)p; p += (size_t)512 * 512 * 2;
    int* bsum = (int*)p; p += (size_t)NSB * 4;
    int* bofs = (int*)p; p += (size_t)NSB * 4;
    float* h3 = (float*)bufA;
    float* asc3 = asrc;
    float* adc3 = adst;

    // graph build (CSR by dst, with self-loops)
    k_detect<<<1, 64, 0, stream>>>(ei, flag, mkeys);
    k_init_deg<<<(NNODES + 255) / 256, 256, 0, stream>>>(deg);
    k_count<<<(NEDGES + 255) / 256, 256, 0, stream>>>(ei, flag, deg);
    k_bsum<<<NSB, 256, 0, stream>>>(deg, bsum);
    k_bscan<<<1, 64, 0, stream>>>(bsum, bofs, offs);
    k_scan_final<<<NSB, 256, 0, stream>>>(deg, bofs, offs, cur);
    k_fill<<<(NEDGES + NNODES + 255) / 256, 256, 0, stream>>>(ei, flag, cur, csr);

    // precision prep: x -> bf16 (bufB), W1/W2 -> bf16 transposed [N][K]
    {
        int n4 = NNODES * FINCH / 4;
        k_f2bf<<<(n4 + 255) / 256, 256, 0, stream>>>(x, bufB, n4);
        dim3 gt(16, 16);
        k_transpose<<<gt, 256, 0, stream>>>(W1, Wt1);
        k_transpose<<<gt, 256, 0, stream>>>(W2, Wt2);
    }

    dim3 gg(4, (NNODES + 127) / 128);   // 128x128 tiles
    int gagg = (NNODES + 3) / 4;
    // layer 1
    mfma_gemm2<<<gg, 512, 0, stream>>>(bufB, Wt1, bufA, NNODES);
    k_alpha8<<<(NNODES * 8 * 64) / 256, 256, 0, stream>>>(bufA, as1, ad1, asrc, adst);
    k_msrc<8><<<128, 256, 0, stream>>>(asrc, mkeys, NNODES * 8);
    agg_v4<true><<<gagg, 256, 0, stream>>>(bufA, asrc, adst, offs, csr, b1, mkeys, bufB);
    // layer 2
    mfma_gemm2<<<gg, 512, 0, stream>>>(bufB, Wt2, bufA, NNODES);
    k_alpha8<<<(NNODES * 8 * 64) / 256, 256, 0, stream>>>(bufA, as2, ad2, asrc, adst);
    k_msrc<8><<<128, 256, 0, stream>>>(asrc, mkeys + 8, NNODES * 8);
    agg_v4<true><<<gagg, 256, 0, stream>>>(bufA, asrc, adst, offs, csr, b2, mkeys + 8, bufB);
    // layer 3 (+ fused log_softmax)
    dim3 g3(1, (NNODES + 63) / 64);
    bgemm64<<<g3, 256, 0, stream>>>(bufB, W3, h3, NNODES, OUTC, 512);
    k_alpha1<<<(NNODES * 64 + 255) / 256, 256, 0, stream>>>(h3, as3, ad3, asc3, adc3);
    k_msrc<1><<<128, 256, 0, stream>>>(asc3, mkeys + 16, NNODES);
    agg_out<<<NNODES, 64, 0, stream>>>(h3, asc3, adc3, offs, csr, b3, mkeys + 16, out);
}